// Round 2
// baseline (358.380 us; speedup 1.0000x reference)
//
#include <hip/hip_runtime.h>
#include <hip/hip_bf16.h>

typedef __bf16 bf16_t;
typedef __bf16 bf16x8 __attribute__((ext_vector_type(8)));
typedef __bf16 bf16x4 __attribute__((ext_vector_type(4)));
typedef float  f32x4  __attribute__((ext_vector_type(4)));

#define HDIM 1024
#define SEQ  2048
#define NHEAD 16
#define HEADD 64

__device__ __forceinline__ void gld_lds16(const void* g, void* l) {
  __builtin_amdgcn_global_load_lds(
      (const __attribute__((address_space(1))) unsigned int*)g,
      (__attribute__((address_space(3))) unsigned int*)l, 16, 0, 0);
}

// ---------------- LayerNorm(fp32 in) -> bf16 out ----------------
__global__ __launch_bounds__(256) void ln_kernel(const float* __restrict__ x,
                                                 const float* __restrict__ gam,
                                                 const float* __restrict__ bet,
                                                 bf16_t* __restrict__ out) {
  int row = blockIdx.x;
  int t = threadIdx.x;
  const float4* xr = (const float4*)(x + (size_t)row * HDIM);
  float4 v = xr[t];
  float s = v.x + v.y + v.z + v.w;
  float ss = v.x*v.x + v.y*v.y + v.z*v.z + v.w*v.w;
  #pragma unroll
  for (int o = 32; o > 0; o >>= 1) {
    s  += __shfl_xor(s, o);
    ss += __shfl_xor(ss, o);
  }
  __shared__ float red[8];
  int w = t >> 6;
  if ((t & 63) == 0) { red[w*2] = s; red[w*2+1] = ss; }
  __syncthreads();
  s  = red[0] + red[2] + red[4] + red[6];
  ss = red[1] + red[3] + red[5] + red[7];
  float mu  = s * (1.0f / HDIM);
  float var = ss * (1.0f / HDIM) - mu * mu;
  float rstd = rsqrtf(var + 1e-5f);
  float4 g4 = ((const float4*)gam)[t];
  float4 b4 = ((const float4*)bet)[t];
  bf16x4 o4;
  o4[0] = (bf16_t)((v.x - mu) * rstd * g4.x + b4.x);
  o4[1] = (bf16_t)((v.y - mu) * rstd * g4.y + b4.y);
  o4[2] = (bf16_t)((v.z - mu) * rstd * g4.z + b4.z);
  o4[3] = (bf16_t)((v.w - mu) * rstd * g4.w + b4.w);
  *(bf16x4*)(out + (size_t)row * HDIM + t * 4) = o4;
}

// ---------------- W[K][N] fp32 -> W^T[N][K] bf16 ----------------
__global__ __launch_bounds__(256) void transpose_cast(const float* __restrict__ W,
                                                      bf16_t* __restrict__ Wt,
                                                      int Kd, int Nd) {
  __shared__ float tile[32][33];
  int n0 = blockIdx.x * 32, k0 = blockIdx.y * 32;
  int tx = threadIdx.x & 31, ty = threadIdx.x >> 5;
  #pragma unroll
  for (int i = 0; i < 4; i++)
    tile[ty + i*8][tx] = W[(size_t)(k0 + ty + i*8) * Nd + n0 + tx];
  __syncthreads();
  #pragma unroll
  for (int i = 0; i < 4; i++)
    Wt[(size_t)(n0 + ty + i*8) * Kd + k0 + tx] = (bf16_t)tile[tx][ty + i*8];
}

// ---------------- GEMM: C[M][N] = A[M][K](bf16) @ Bt[N][K]^T + bias ----------------
// EPI: 0 = bias, bf16 out; 1 = bias + fp32 residual, fp32 out; 2 = bias + exact GELU, bf16 out
template<int EPI>
__global__ __launch_bounds__(256, 2)
void gemm_bt(const bf16_t* __restrict__ A, const bf16_t* __restrict__ Bt,
             const float* __restrict__ bias, const float* __restrict__ resid,
             void* __restrict__ outp, int M, int N, int K) {
  __shared__ bf16_t As[128*32];
  __shared__ bf16_t Bs[128*32];
  int t = threadIdx.x;
  int w = t >> 6, l = t & 63;
  int wr = w >> 1, wc = w & 1;
  size_t m0 = (size_t)blockIdx.y * 128, n0 = (size_t)blockIdx.x * 128;

  f32x4 acc[4][4];
  #pragma unroll
  for (int m = 0; m < 4; m++)
    #pragma unroll
    for (int n = 0; n < 4; n++) acc[m][n] = (f32x4)(0.0f);

  int srow = t >> 2, scol = (t & 3) * 8;
  const bf16_t* ag = A  + (m0 + srow) * K + scol;
  const bf16_t* bg = Bt + (n0 + srow) * K + scol;
  bf16_t* al = As + srow * 32 + scol;
  bf16_t* bl = Bs + srow * 32 + scol;

  int lr = l & 15, lc = (l >> 4) * 8;

  for (int k0 = 0; k0 < K; k0 += 32) {
    gld_lds16(ag + k0, al);
    gld_lds16(ag + k0 + (size_t)64 * K, al + 64*32);
    gld_lds16(bg + k0, bl);
    gld_lds16(bg + k0 + (size_t)64 * K, bl + 64*32);
    __syncthreads();
    bf16x8 af[4], bfr[4];
    #pragma unroll
    for (int m = 0; m < 4; m++)
      af[m] = *(const bf16x8*)(As + (wr*64 + m*16 + lr)*32 + lc);
    #pragma unroll
    for (int n = 0; n < 4; n++)
      bfr[n] = *(const bf16x8*)(Bs + (wc*64 + n*16 + lr)*32 + lc);
    #pragma unroll
    for (int m = 0; m < 4; m++)
      #pragma unroll
      for (int n = 0; n < 4; n++)
        acc[m][n] = __builtin_amdgcn_mfma_f32_16x16x32_bf16(af[m], bfr[n], acc[m][n], 0, 0, 0);
    __syncthreads();
  }

  int r0 = (l >> 4) * 4, c0 = l & 15;
  #pragma unroll
  for (int m = 0; m < 4; m++) {
    #pragma unroll
    for (int n = 0; n < 4; n++) {
      size_t row = m0 + wr*64 + m*16 + r0;
      size_t col = n0 + wc*64 + n*16 + c0;
      float bv = bias[col];
      #pragma unroll
      for (int r = 0; r < 4; r++) {
        float vv = acc[m][n][r] + bv;
        size_t idx = (row + r) * (size_t)N + col;
        if (EPI == 0) {
          ((bf16_t*)outp)[idx] = (bf16_t)vv;
        } else if (EPI == 1) {
          ((float*)outp)[idx] = vv + resid[idx];
        } else {
          float ge = 0.5f * vv * (1.0f + erff(vv * 0.70710678118f));
          ((bf16_t*)outp)[idx] = (bf16_t)ge;
        }
      }
    }
  }
}

// ---------------- causal flash attention ----------------
// qkv: [4096][3072] bf16, row=(b,s), cols: q=h*64+d, k=1024+h*64+d, v=2048+h*64+d
// out: [4096][1024] bf16 (b,s,h*64+d)
__global__ __launch_bounds__(256)
void attn_kernel(const bf16_t* __restrict__ qkv, bf16_t* __restrict__ out) {
  int qt = blockIdx.x & 31;
  int bh = blockIdx.x >> 5;
  int b = bh >> 4, h = bh & 15;
  int t = threadIdx.x, w = t >> 6, l = t & 63;

  __shared__ bf16_t Ks[64*64];      // XOR-swizzled [krow][hd]
  __shared__ bf16_t Vt[64*72];      // V^T padded: [d][krow], stride 72
  __shared__ bf16_t Ps[4][16*64];   // per-wave P tile, XOR-swizzled

  const size_t RS = 3 * HDIM;  // 3072
  const bf16_t* qb = qkv + (size_t)b * SEQ * RS + h * HEADD;
  const bf16_t* kb = qb + HDIM;
  const bf16_t* vb = qb + 2 * HDIM;

  int lr = l & 15, lg = l >> 4;

  bf16x8 qf[2];
  {
    size_t qrow = (size_t)qt * 64 + w * 16 + lr;
    qf[0] = *(const bf16x8*)(qb + qrow * RS + lg * 8);
    qf[1] = *(const bf16x8*)(qb + qrow * RS + 32 + lg * 8);
  }

  f32x4 o[4];
  #pragma unroll
  for (int d = 0; d < 4; d++) o[d] = (f32x4)(0.0f);
  float mrow[4], lrow[4];
  #pragma unroll
  for (int r = 0; r < 4; r++) { mrow[r] = -1e30f; lrow[r] = 0.0f; }

  int srow = t >> 2, sc0 = (t & 3) * 16;
  int nkt = qt + 1;
  for (int kt = 0; kt < nkt; kt++) {
    { // stage K (swizzled) and V^T (padded)
      const bf16_t* kg = kb + (size_t)(kt*64 + srow) * RS + sc0;
      bf16x8 k0v = *(const bf16x8*)kg;
      bf16x8 k1v = *(const bf16x8*)(kg + 8);
      int ba = srow * 128 + sc0 * 2;
      int sw = (srow & 7) << 4;
      *(bf16x8*)((char*)Ks + ((ba) ^ sw))      = k0v;
      *(bf16x8*)((char*)Ks + ((ba + 16) ^ sw)) = k1v;
      const bf16_t* vg = vb + (size_t)(kt*64 + srow) * RS + sc0;
      bf16x8 v0 = *(const bf16x8*)vg;
      bf16x8 v1 = *(const bf16x8*)(vg + 8);
      #pragma unroll
      for (int i = 0; i < 8; i++) {
        Vt[(sc0 + i)     * 72 + srow] = v0[i];
        Vt[(sc0 + 8 + i) * 72 + srow] = v1[i];
      }
    }
    __syncthreads();

    // QK^T
    f32x4 sc[4];
    #pragma unroll
    for (int kt2 = 0; kt2 < 4; kt2++) {
      sc[kt2] = (f32x4)(0.0f);
      #pragma unroll
      for (int kk = 0; kk < 2; kk++) {
        int row = kt2 * 16 + lr;
        int off = (row * 128 + kk * 64 + lg * 16) ^ ((row & 7) << 4);
        bf16x8 kf = *(const bf16x8*)((char*)Ks + off);
        sc[kt2] = __builtin_amdgcn_mfma_f32_16x16x32_bf16(qf[kk], kf, sc[kt2], 0, 0, 0);
      }
    }
    // scale + causal mask
    int qrow0 = qt*64 + w*16 + lg*4;
    #pragma unroll
    for (int kt2 = 0; kt2 < 4; kt2++) {
      int kcol = kt*64 + kt2*16 + lr;
      #pragma unroll
      for (int r = 0; r < 4; r++) {
        float vv = sc[kt2][r] * 0.125f;
        sc[kt2][r] = (kcol > qrow0 + r) ? -1e30f : vv;
      }
    }
    // online softmax (per q-row: reduce across the 16-lane column group)
    float alpha[4];
    #pragma unroll
    for (int r = 0; r < 4; r++) {
      float tm = fmaxf(fmaxf(sc[0][r], sc[1][r]), fmaxf(sc[2][r], sc[3][r]));
      #pragma unroll
      for (int o2 = 1; o2 < 16; o2 <<= 1) tm = fmaxf(tm, __shfl_xor(tm, o2));
      float nm = fmaxf(mrow[r], tm);
      alpha[r] = __expf(mrow[r] - nm);
      mrow[r] = nm;
    }
    #pragma unroll
    for (int r = 0; r < 4; r++) {
      float acc = 0.0f;
      #pragma unroll
      for (int kt2 = 0; kt2 < 4; kt2++) {
        float p = __expf(sc[kt2][r] - mrow[r]);
        sc[kt2][r] = p;
        acc += p;
      }
      #pragma unroll
      for (int o2 = 1; o2 < 16; o2 <<= 1) acc += __shfl_xor(acc, o2);
      lrow[r] = lrow[r] * alpha[r] + acc;
    }
    #pragma unroll
    for (int d = 0; d < 4; d++)
      #pragma unroll
      for (int r = 0; r < 4; r++) o[d][r] *= alpha[r];

    // P -> LDS (bf16, swizzled), wave-private
    bf16_t* pw = Ps[w];
    #pragma unroll
    for (int kt2 = 0; kt2 < 4; kt2++) {
      #pragma unroll
      for (int r = 0; r < 4; r++) {
        int prow = lg * 4 + r;
        int off = (prow * 128 + (kt2 * 16 + lr) * 2) ^ ((prow & 7) << 4);
        *(bf16_t*)((char*)pw + off) = (bf16_t)sc[kt2][r];
      }
    }
    asm volatile("s_waitcnt lgkmcnt(0)" ::: "memory");
    // PV
    #pragma unroll
    for (int d = 0; d < 4; d++) {
      #pragma unroll
      for (int kk = 0; kk < 2; kk++) {
        int poff = (lr * 128 + kk * 64 + lg * 16) ^ ((lr & 7) << 4);
        bf16x8 pf = *(const bf16x8*)((char*)pw + poff);
        bf16x8 vf = *(const bf16x8*)(Vt + (d*16 + lr) * 72 + kk * 32 + lg * 8);
        o[d] = __builtin_amdgcn_mfma_f32_16x16x32_bf16(pf, vf, o[d], 0, 0, 0);
      }
    }
    __syncthreads();
  }

  #pragma unroll
  for (int d = 0; d < 4; d++) {
    #pragma unroll
    for (int r = 0; r < 4; r++) {
      size_t qrow = (size_t)qt*64 + w*16 + lg*4 + r;
      out[((size_t)b * SEQ + qrow) * HDIM + h * HEADD + d*16 + lr] =
          (bf16_t)(o[d][r] / lrow[r]);
    }
  }
}

extern "C" void kernel_launch(void* const* d_in, const int* in_sizes, int n_in,
                              void* d_out, int out_size, void* d_ws, size_t ws_size,
                              hipStream_t stream) {
  (void)in_sizes; (void)n_in; (void)out_size; (void)ws_size;
  const float* x     = (const float*)d_in[0];
  const float* w_qkv = (const float*)d_in[1];
  const float* b_qkv = (const float*)d_in[2];
  const float* w_out = (const float*)d_in[3];
  const float* b_out = (const float*)d_in[4];
  const float* ln1_g = (const float*)d_in[5];
  const float* ln1_b = (const float*)d_in[6];
  const float* ln2_g = (const float*)d_in[7];
  const float* ln2_b = (const float*)d_in[8];
  const float* w1    = (const float*)d_in[9];
  const float* b1    = (const float*)d_in[10];
  const float* w2    = (const float*)d_in[11];
  const float* b2    = (const float*)d_in[12];
  float* out = (float*)d_out;

  char* ws = (char*)d_ws;
  size_t off = 0;
  auto alloc = [&](size_t bytes) -> void* {
    void* p = ws + off;
    off += (bytes + 255) & ~(size_t)255;
    return p;
  };
  // total ~88 MB
  bf16_t* wqkvT = (bf16_t*)alloc((size_t)3072*1024*2);
  bf16_t* woutT = (bf16_t*)alloc((size_t)1024*1024*2);
  bf16_t* w1T   = (bf16_t*)alloc((size_t)4096*1024*2);
  bf16_t* w2T   = (bf16_t*)alloc((size_t)1024*4096*2);
  bf16_t* ln1o  = (bf16_t*)alloc((size_t)4096*1024*2);   // reused as h2
  bf16_t* qkvb  = (bf16_t*)alloc((size_t)4096*4096*2);   // qkv (4096x3072), reused as gelu-act (4096x4096)
  bf16_t* attno = (bf16_t*)alloc((size_t)4096*1024*2);
  float*  x2    = (float*) alloc((size_t)4096*1024*4);
  bf16_t* h2 = ln1o;
  bf16_t* g  = qkvb;

  dim3 blk(256);
  transpose_cast<<<dim3(3072/32, 1024/32), blk, 0, stream>>>(w_qkv, wqkvT, 1024, 3072);
  transpose_cast<<<dim3(1024/32, 1024/32), blk, 0, stream>>>(w_out, woutT, 1024, 1024);
  transpose_cast<<<dim3(4096/32, 1024/32), blk, 0, stream>>>(w1,    w1T,   1024, 4096);
  transpose_cast<<<dim3(1024/32, 4096/32), blk, 0, stream>>>(w2,    w2T,   4096, 1024);

  ln_kernel<<<4096, blk, 0, stream>>>(x, ln1_g, ln1_b, ln1o);
  gemm_bt<0><<<dim3(24, 32), blk, 0, stream>>>(ln1o, wqkvT, b_qkv, nullptr, qkvb, 4096, 3072, 1024);
  attn_kernel<<<1024, blk, 0, stream>>>(qkvb, attno);
  gemm_bt<1><<<dim3(8, 32), blk, 0, stream>>>(attno, woutT, b_out, x, x2, 4096, 1024, 1024);
  ln_kernel<<<4096, blk, 0, stream>>>(x2, ln2_g, ln2_b, h2);
  gemm_bt<2><<<dim3(32, 32), blk, 0, stream>>>(h2, w1T, b1, nullptr, g, 4096, 4096, 1024);
  gemm_bt<1><<<dim3(8, 32), blk, 0, stream>>>(g, w2T, b2, x2, out, 4096, 1024, 4096);
}

// Round 3
// 303.054 us; speedup vs baseline: 1.1826x; 1.1826x over previous
//
#include <hip/hip_runtime.h>
#include <hip/hip_bf16.h>

typedef __bf16 bf16_t;
typedef __bf16 bf16x8 __attribute__((ext_vector_type(8)));
typedef __bf16 bf16x4 __attribute__((ext_vector_type(4)));
typedef float  f32x4  __attribute__((ext_vector_type(4)));

#define HDIM 1024
#define SEQ  2048
#define NHEAD 16
#define HEADD 64

__device__ __forceinline__ void gld_lds16(const void* g, void* l) {
  __builtin_amdgcn_global_load_lds(
      (const __attribute__((address_space(1))) unsigned int*)g,
      (__attribute__((address_space(3))) unsigned int*)l, 16, 0, 0);
}

// ---------------- LayerNorm(fp32 in) -> bf16 out ----------------
__global__ __launch_bounds__(256) void ln_kernel(const float* __restrict__ x,
                                                 const float* __restrict__ gam,
                                                 const float* __restrict__ bet,
                                                 bf16_t* __restrict__ out) {
  int row = blockIdx.x;
  int t = threadIdx.x;
  const float4* xr = (const float4*)(x + (size_t)row * HDIM);
  float4 v = xr[t];
  float s = v.x + v.y + v.z + v.w;
  float ss = v.x*v.x + v.y*v.y + v.z*v.z + v.w*v.w;
  #pragma unroll
  for (int o = 32; o > 0; o >>= 1) {
    s  += __shfl_xor(s, o);
    ss += __shfl_xor(ss, o);
  }
  __shared__ float red[8];
  int w = t >> 6;
  if ((t & 63) == 0) { red[w*2] = s; red[w*2+1] = ss; }
  __syncthreads();
  s  = red[0] + red[2] + red[4] + red[6];
  ss = red[1] + red[3] + red[5] + red[7];
  float mu  = s * (1.0f / HDIM);
  float var = ss * (1.0f / HDIM) - mu * mu;
  float rstd = rsqrtf(var + 1e-5f);
  float4 g4 = ((const float4*)gam)[t];
  float4 b4 = ((const float4*)bet)[t];
  bf16x4 o4;
  o4[0] = (bf16_t)((v.x - mu) * rstd * g4.x + b4.x);
  o4[1] = (bf16_t)((v.y - mu) * rstd * g4.y + b4.y);
  o4[2] = (bf16_t)((v.z - mu) * rstd * g4.z + b4.z);
  o4[3] = (bf16_t)((v.w - mu) * rstd * g4.w + b4.w);
  *(bf16x4*)(out + (size_t)row * HDIM + t * 4) = o4;
}

// ---------------- W[K][N] fp32 -> W^T[N][K] bf16 ----------------
__global__ __launch_bounds__(256) void transpose_cast(const float* __restrict__ W,
                                                      bf16_t* __restrict__ Wt,
                                                      int Kd, int Nd) {
  __shared__ float tile[32][33];
  int n0 = blockIdx.x * 32, k0 = blockIdx.y * 32;
  int tx = threadIdx.x & 31, ty = threadIdx.x >> 5;
  #pragma unroll
  for (int i = 0; i < 4; i++)
    tile[ty + i*8][tx] = W[(size_t)(k0 + ty + i*8) * Nd + n0 + tx];
  __syncthreads();
  #pragma unroll
  for (int i = 0; i < 4; i++)
    Wt[(size_t)(n0 + ty + i*8) * Kd + k0 + tx] = (bf16_t)tile[tx][ty + i*8];
}

// ---------------- GEMM: C[M][N] = A[M][K](bf16) @ Bt[N][K]^T + bias ----------------
// EPI: 0 = bias, bf16 out; 1 = bias + fp32 residual, fp32 out; 2 = bias + exact GELU, bf16 out
template<int EPI>
__global__ __launch_bounds__(256, 2)
void gemm_bt(const bf16_t* __restrict__ A, const bf16_t* __restrict__ Bt,
             const float* __restrict__ bias, const float* __restrict__ resid,
             void* __restrict__ outp, int M, int N, int K) {
  __shared__ bf16_t As[128*32];
  __shared__ bf16_t Bs[128*32];
  int t = threadIdx.x;
  int w = t >> 6, l = t & 63;
  int wr = w >> 1, wc = w & 1;
  size_t m0 = (size_t)blockIdx.y * 128, n0 = (size_t)blockIdx.x * 128;

  f32x4 acc[4][4];
  #pragma unroll
  for (int m = 0; m < 4; m++)
    #pragma unroll
    for (int n = 0; n < 4; n++) acc[m][n] = (f32x4)(0.0f);

  int srow = t >> 2, scol = (t & 3) * 8;
  const bf16_t* ag = A  + (m0 + srow) * K + scol;
  const bf16_t* bg = Bt + (n0 + srow) * K + scol;
  bf16_t* al = As + srow * 32 + scol;
  bf16_t* bl = Bs + srow * 32 + scol;

  int lr = l & 15, lc = (l >> 4) * 8;

  for (int k0 = 0; k0 < K; k0 += 32) {
    gld_lds16(ag + k0, al);
    gld_lds16(ag + k0 + (size_t)64 * K, al + 64*32);
    gld_lds16(bg + k0, bl);
    gld_lds16(bg + k0 + (size_t)64 * K, bl + 64*32);
    __syncthreads();
    bf16x8 af[4], bfr[4];
    #pragma unroll
    for (int m = 0; m < 4; m++)
      af[m] = *(const bf16x8*)(As + (wr*64 + m*16 + lr)*32 + lc);
    #pragma unroll
    for (int n = 0; n < 4; n++)
      bfr[n] = *(const bf16x8*)(Bs + (wc*64 + n*16 + lr)*32 + lc);
    #pragma unroll
    for (int m = 0; m < 4; m++)
      #pragma unroll
      for (int n = 0; n < 4; n++)
        acc[m][n] = __builtin_amdgcn_mfma_f32_16x16x32_bf16(af[m], bfr[n], acc[m][n], 0, 0, 0);
    __syncthreads();
  }

  int r0 = (l >> 4) * 4, c0 = l & 15;
  #pragma unroll
  for (int m = 0; m < 4; m++) {
    #pragma unroll
    for (int n = 0; n < 4; n++) {
      size_t row = m0 + wr*64 + m*16 + r0;
      size_t col = n0 + wc*64 + n*16 + c0;
      float bv = bias[col];
      #pragma unroll
      for (int r = 0; r < 4; r++) {
        float vv = acc[m][n][r] + bv;
        size_t idx = (row + r) * (size_t)N + col;
        if (EPI == 0) {
          ((bf16_t*)outp)[idx] = (bf16_t)vv;
        } else if (EPI == 1) {
          ((float*)outp)[idx] = vv + resid[idx];
        } else {
          float ge = 0.5f * vv * (1.0f + erff(vv * 0.70710678118f));
          ((bf16_t*)outp)[idx] = (bf16_t)ge;
        }
      }
    }
  }
}

// ---------------- causal flash attention ----------------
// qkv: [4096][3072] bf16, row=(b,s), cols: q=h*64+d, k=1024+h*64+d, v=2048+h*64+d
// out: [4096][1024] bf16 (b,s,h*64+d)
// Block mapping is REVERSED in qt so the longest (qt=31) blocks dispatch first.
__global__ __launch_bounds__(256)
void attn_kernel(const bf16_t* __restrict__ qkv, bf16_t* __restrict__ out) {
  int qt = 31 - (blockIdx.x >> 5);
  int bh = blockIdx.x & 31;
  int b = bh >> 4, h = bh & 15;
  int t = threadIdx.x, w = t >> 6, l = t & 63;

  __shared__ bf16_t Ks[64*64];      // XOR-swizzled [krow][hd]
  __shared__ bf16_t Vt[64*72];      // V^T padded: [d][krow], stride 72
  __shared__ bf16_t Ps[4][16*64];   // per-wave P tile, XOR-swizzled

  const size_t RS = 3 * HDIM;  // 3072
  const bf16_t* qb = qkv + (size_t)b * SEQ * RS + h * HEADD;
  const bf16_t* kb = qb + HDIM;
  const bf16_t* vb = qb + 2 * HDIM;

  int lr = l & 15, lg = l >> 4;

  bf16x8 qf[2];
  {
    size_t qrow = (size_t)qt * 64 + w * 16 + lr;
    qf[0] = *(const bf16x8*)(qb + qrow * RS + lg * 8);
    qf[1] = *(const bf16x8*)(qb + qrow * RS + 32 + lg * 8);
  }

  f32x4 o[4];
  #pragma unroll
  for (int d = 0; d < 4; d++) o[d] = (f32x4)(0.0f);
  float mrow[4], lsum[4];
  #pragma unroll
  for (int r = 0; r < 4; r++) { mrow[r] = -1e30f; lsum[r] = 0.0f; }

  // scale with log2(e) folded in: softmax uses exp2
  const float SCALE = 0.125f * 1.44269504f;

  int srow = t >> 2, sc0 = (t & 3) * 16;
  int nkt = qt + 1;

  const bf16_t* kg0 = kb + (size_t)srow * RS + sc0;
  const bf16_t* vg0 = vb + (size_t)srow * RS + sc0;

  // prefetch regs for tile 0
  bf16x8 kr0 = *(const bf16x8*)kg0;
  bf16x8 kr1 = *(const bf16x8*)(kg0 + 8);
  bf16x8 vr0 = *(const bf16x8*)vg0;
  bf16x8 vr1 = *(const bf16x8*)(vg0 + 8);

  for (int kt = 0; kt < nkt; kt++) {
    { // write staged regs to LDS: K swizzled, V transposed (padded stride 72)
      int ba = srow * 128 + sc0 * 2;
      int sw = (srow & 7) << 4;
      *(bf16x8*)((char*)Ks + ((ba) ^ sw))      = kr0;
      *(bf16x8*)((char*)Ks + ((ba + 16) ^ sw)) = kr1;
      #pragma unroll
      for (int i = 0; i < 8; i++) {
        Vt[(sc0 + i)     * 72 + srow] = vr0[i];
        Vt[(sc0 + 8 + i) * 72 + srow] = vr1[i];
      }
    }
    __syncthreads();

    // issue global loads for tile kt+1 — latency hides under compute below
    if (kt + 1 < nkt) {
      const bf16_t* kg = kg0 + (size_t)(kt + 1) * 64 * RS;
      const bf16_t* vg = vg0 + (size_t)(kt + 1) * 64 * RS;
      kr0 = *(const bf16x8*)kg;
      kr1 = *(const bf16x8*)(kg + 8);
      vr0 = *(const bf16x8*)vg;
      vr1 = *(const bf16x8*)(vg + 8);
    }

    // QK^T
    f32x4 sc[4];
    #pragma unroll
    for (int kt2 = 0; kt2 < 4; kt2++) {
      sc[kt2] = (f32x4)(0.0f);
      #pragma unroll
      for (int kk = 0; kk < 2; kk++) {
        int row = kt2 * 16 + lr;
        int off = (row * 128 + kk * 64 + lg * 16) ^ ((row & 7) << 4);
        bf16x8 kf = *(const bf16x8*)((char*)Ks + off);
        sc[kt2] = __builtin_amdgcn_mfma_f32_16x16x32_bf16(qf[kk], kf, sc[kt2], 0, 0, 0);
      }
    }
    // scale (log2 domain); causal mask only on the diagonal tile
    #pragma unroll
    for (int kt2 = 0; kt2 < 4; kt2++) {
      #pragma unroll
      for (int r = 0; r < 4; r++) sc[kt2][r] *= SCALE;
    }
    if (kt == qt) {
      int qrow0 = qt*64 + w*16 + lg*4;
      #pragma unroll
      for (int kt2 = 0; kt2 < 4; kt2++) {
        int kcol = kt*64 + kt2*16 + lr;
        #pragma unroll
        for (int r = 0; r < 4; r++)
          if (kcol > qrow0 + r) sc[kt2][r] = -1e30f;
      }
    }
    // online softmax (exp2 domain); sum reduction deferred to the end
    float alpha[4];
    #pragma unroll
    for (int r = 0; r < 4; r++) {
      float tm = fmaxf(fmaxf(sc[0][r], sc[1][r]), fmaxf(sc[2][r], sc[3][r]));
      #pragma unroll
      for (int o2 = 1; o2 < 16; o2 <<= 1) tm = fmaxf(tm, __shfl_xor(tm, o2));
      float nm = fmaxf(mrow[r], tm);
      alpha[r] = exp2f(mrow[r] - nm);
      mrow[r] = nm;
    }
    #pragma unroll
    for (int r = 0; r < 4; r++) {
      float p0 = exp2f(sc[0][r] - mrow[r]);
      float p1 = exp2f(sc[1][r] - mrow[r]);
      float p2 = exp2f(sc[2][r] - mrow[r]);
      float p3 = exp2f(sc[3][r] - mrow[r]);
      sc[0][r] = p0; sc[1][r] = p1; sc[2][r] = p2; sc[3][r] = p3;
      lsum[r] = lsum[r] * alpha[r] + (p0 + p1 + p2 + p3);
    }
    #pragma unroll
    for (int d = 0; d < 4; d++)
      #pragma unroll
      for (int r = 0; r < 4; r++) o[d][r] *= alpha[r];

    // P -> LDS (bf16, swizzled), wave-private
    bf16_t* pw = Ps[w];
    #pragma unroll
    for (int kt2 = 0; kt2 < 4; kt2++) {
      #pragma unroll
      for (int r = 0; r < 4; r++) {
        int prow = lg * 4 + r;
        int off = (prow * 128 + (kt2 * 16 + lr) * 2) ^ ((prow & 7) << 4);
        *(bf16_t*)((char*)pw + off) = (bf16_t)sc[kt2][r];
      }
    }
    asm volatile("s_waitcnt lgkmcnt(0)" ::: "memory");
    // PV
    #pragma unroll
    for (int d = 0; d < 4; d++) {
      #pragma unroll
      for (int kk = 0; kk < 2; kk++) {
        int poff = (lr * 128 + kk * 64 + lg * 16) ^ ((lr & 7) << 4);
        bf16x8 pf = *(const bf16x8*)((char*)pw + poff);
        bf16x8 vf = *(const bf16x8*)(Vt + (d*16 + lr) * 72 + kk * 32 + lg * 8);
        o[d] = __builtin_amdgcn_mfma_f32_16x16x32_bf16(pf, vf, o[d], 0, 0, 0);
      }
    }
    __syncthreads();
  }

  // deferred 16-lane sum reduction (once, not per tile)
  #pragma unroll
  for (int r = 0; r < 4; r++) {
    float acc = lsum[r];
    #pragma unroll
    for (int o2 = 1; o2 < 16; o2 <<= 1) acc += __shfl_xor(acc, o2);
    lsum[r] = acc;
  }

  #pragma unroll
  for (int d = 0; d < 4; d++) {
    #pragma unroll
    for (int r = 0; r < 4; r++) {
      size_t qrow = (size_t)qt*64 + w*16 + lg*4 + r;
      out[((size_t)b * SEQ + qrow) * HDIM + h * HEADD + d*16 + lr] =
          (bf16_t)(o[d][r] / lsum[r]);
    }
  }
}

extern "C" void kernel_launch(void* const* d_in, const int* in_sizes, int n_in,
                              void* d_out, int out_size, void* d_ws, size_t ws_size,
                              hipStream_t stream) {
  (void)in_sizes; (void)n_in; (void)out_size; (void)ws_size;
  const float* x     = (const float*)d_in[0];
  const float* w_qkv = (const float*)d_in[1];
  const float* b_qkv = (const float*)d_in[2];
  const float* w_out = (const float*)d_in[3];
  const float* b_out = (const float*)d_in[4];
  const float* ln1_g = (const float*)d_in[5];
  const float* ln1_b = (const float*)d_in[6];
  const float* ln2_g = (const float*)d_in[7];
  const float* ln2_b = (const float*)d_in[8];
  const float* w1    = (const float*)d_in[9];
  const float* b1    = (const float*)d_in[10];
  const float* w2    = (const float*)d_in[11];
  const float* b2    = (const float*)d_in[12];
  float* out = (float*)d_out;

  char* ws = (char*)d_ws;
  size_t off = 0;
  auto alloc = [&](size_t bytes) -> void* {
    void* p = ws + off;
    off += (bytes + 255) & ~(size_t)255;
    return p;
  };
  // total ~88 MB
  bf16_t* wqkvT = (bf16_t*)alloc((size_t)3072*1024*2);
  bf16_t* woutT = (bf16_t*)alloc((size_t)1024*1024*2);
  bf16_t* w1T   = (bf16_t*)alloc((size_t)4096*1024*2);
  bf16_t* w2T   = (bf16_t*)alloc((size_t)1024*4096*2);
  bf16_t* ln1o  = (bf16_t*)alloc((size_t)4096*1024*2);   // reused as h2
  bf16_t* qkvb  = (bf16_t*)alloc((size_t)4096*4096*2);   // qkv (4096x3072), reused as gelu-act (4096x4096)
  bf16_t* attno = (bf16_t*)alloc((size_t)4096*1024*2);
  float*  x2    = (float*) alloc((size_t)4096*1024*4);
  bf16_t* h2 = ln1o;
  bf16_t* g  = qkvb;

  dim3 blk(256);
  transpose_cast<<<dim3(3072/32, 1024/32), blk, 0, stream>>>(w_qkv, wqkvT, 1024, 3072);
  transpose_cast<<<dim3(1024/32, 1024/32), blk, 0, stream>>>(w_out, woutT, 1024, 1024);
  transpose_cast<<<dim3(4096/32, 1024/32), blk, 0, stream>>>(w1,    w1T,   1024, 4096);
  transpose_cast<<<dim3(1024/32, 4096/32), blk, 0, stream>>>(w2,    w2T,   4096, 1024);

  ln_kernel<<<4096, blk, 0, stream>>>(x, ln1_g, ln1_b, ln1o);
  gemm_bt<0><<<dim3(24, 32), blk, 0, stream>>>(ln1o, wqkvT, b_qkv, nullptr, qkvb, 4096, 3072, 1024);
  attn_kernel<<<1024, blk, 0, stream>>>(qkvb, attno);
  gemm_bt<1><<<dim3(8, 32), blk, 0, stream>>>(attno, woutT, b_out, x, x2, 4096, 1024, 1024);
  ln_kernel<<<4096, blk, 0, stream>>>(x2, ln2_g, ln2_b, h2);
  gemm_bt<2><<<dim3(32, 32), blk, 0, stream>>>(h2, w1T, b1, nullptr, g, 4096, 4096, 1024);
  gemm_bt<1><<<dim3(8, 32), blk, 0, stream>>>(g, w2T, b2, x2, out, 4096, 1024, 4096);
}

// Round 4
// 295.514 us; speedup vs baseline: 1.2127x; 1.0255x over previous
//
#include <hip/hip_runtime.h>
#include <hip/hip_bf16.h>

typedef __bf16 bf16_t;
typedef __bf16 bf16x8 __attribute__((ext_vector_type(8)));
typedef __bf16 bf16x4 __attribute__((ext_vector_type(4)));
typedef float  f32x4  __attribute__((ext_vector_type(4)));

#define HDIM 1024
#define SEQ  2048
#define NHEAD 16
#define HEADD 64

__device__ __forceinline__ void gld_lds16(const void* g, void* l) {
  __builtin_amdgcn_global_load_lds(
      (const __attribute__((address_space(1))) unsigned int*)g,
      (__attribute__((address_space(3))) unsigned int*)l, 16, 0, 0);
}

// ---------------- LayerNorm(fp32 in) -> bf16 out ----------------
__global__ __launch_bounds__(256) void ln_kernel(const float* __restrict__ x,
                                                 const float* __restrict__ gam,
                                                 const float* __restrict__ bet,
                                                 bf16_t* __restrict__ out) {
  int row = blockIdx.x;
  int t = threadIdx.x;
  const float4* xr = (const float4*)(x + (size_t)row * HDIM);
  float4 v = xr[t];
  float s = v.x + v.y + v.z + v.w;
  float ss = v.x*v.x + v.y*v.y + v.z*v.z + v.w*v.w;
  #pragma unroll
  for (int o = 32; o > 0; o >>= 1) {
    s  += __shfl_xor(s, o);
    ss += __shfl_xor(ss, o);
  }
  __shared__ float red[8];
  int w = t >> 6;
  if ((t & 63) == 0) { red[w*2] = s; red[w*2+1] = ss; }
  __syncthreads();
  s  = red[0] + red[2] + red[4] + red[6];
  ss = red[1] + red[3] + red[5] + red[7];
  float mu  = s * (1.0f / HDIM);
  float var = ss * (1.0f / HDIM) - mu * mu;
  float rstd = rsqrtf(var + 1e-5f);
  float4 g4 = ((const float4*)gam)[t];
  float4 b4 = ((const float4*)bet)[t];
  bf16x4 o4;
  o4[0] = (bf16_t)((v.x - mu) * rstd * g4.x + b4.x);
  o4[1] = (bf16_t)((v.y - mu) * rstd * g4.y + b4.y);
  o4[2] = (bf16_t)((v.z - mu) * rstd * g4.z + b4.z);
  o4[3] = (bf16_t)((v.w - mu) * rstd * g4.w + b4.w);
  *(bf16x4*)(out + (size_t)row * HDIM + t * 4) = o4;
}

// ---------------- W[K][N] fp32 -> W^T[N][K] bf16 ----------------
__global__ __launch_bounds__(256) void transpose_cast(const float* __restrict__ W,
                                                      bf16_t* __restrict__ Wt,
                                                      int Kd, int Nd) {
  __shared__ float tile[32][33];
  int n0 = blockIdx.x * 32, k0 = blockIdx.y * 32;
  int tx = threadIdx.x & 31, ty = threadIdx.x >> 5;
  #pragma unroll
  for (int i = 0; i < 4; i++)
    tile[ty + i*8][tx] = W[(size_t)(k0 + ty + i*8) * Nd + n0 + tx];
  __syncthreads();
  #pragma unroll
  for (int i = 0; i < 4; i++)
    Wt[(size_t)(n0 + ty + i*8) * Kd + k0 + tx] = (bf16_t)tile[tx][ty + i*8];
}

// tanh-form GELU, exp2-based (v_exp_f32 is natively 2^x); ~8 VALU ops
__device__ __forceinline__ float gelu_fast(float x) {
  float y = 0.7978845608f * (x + 0.044715f * x * x * x);
  float u = exp2f(y * 2.885390082f);           // e^(2y)
  float th = 1.0f - 2.0f * __builtin_amdgcn_rcpf(u + 1.0f);
  return 0.5f * x * (1.0f + th);
}

// ---------------- GEMM: C[M][N] = A[M][K](bf16) @ Bt[N][K]^T + bias ----------------
// EPI: 0 = bias, bf16 out; 1 = bias + fp32 residual, fp32 out; 2 = bias + GELU, bf16 out
// BN: 128 (4 n-frags/wave) or 64 (2 n-frags/wave, grid has 2x blocks for small N)
template<int EPI, int BN>
__global__ __launch_bounds__(256, 2)
void gemm_bt(const bf16_t* __restrict__ A, const bf16_t* __restrict__ Bt,
             const float* __restrict__ bias, const float* __restrict__ resid,
             void* __restrict__ outp, int M, int N, int K) {
  constexpr int NFRAG = BN / 32;   // 4 for BN=128, 2 for BN=64
  __shared__ bf16_t As[128*32];
  __shared__ bf16_t Bs[BN*32];
  int t = threadIdx.x;
  int w = t >> 6, l = t & 63;
  int wr = w >> 1, wc = w & 1;
  size_t m0 = (size_t)blockIdx.y * 128, n0 = (size_t)blockIdx.x * BN;

  f32x4 acc[4][NFRAG];
  #pragma unroll
  for (int m = 0; m < 4; m++)
    #pragma unroll
    for (int n = 0; n < NFRAG; n++) acc[m][n] = (f32x4)(0.0f);

  int srow = t >> 2, scol = (t & 3) * 8;
  const bf16_t* ag = A  + (m0 + srow) * K + scol;
  const bf16_t* bg = Bt + (n0 + srow) * K + scol;
  bf16_t* al = As + srow * 32 + scol;
  bf16_t* bl = Bs + srow * 32 + scol;

  int lr = l & 15, lc = (l >> 4) * 8;

  for (int k0 = 0; k0 < K; k0 += 32) {
    gld_lds16(ag + k0, al);
    gld_lds16(ag + k0 + (size_t)64 * K, al + 64*32);
    gld_lds16(bg + k0, bl);
    if constexpr (BN == 128)
      gld_lds16(bg + k0 + (size_t)64 * K, bl + 64*32);
    __syncthreads();
    bf16x8 af[4], bfr[NFRAG];
    #pragma unroll
    for (int m = 0; m < 4; m++)
      af[m] = *(const bf16x8*)(As + (wr*64 + m*16 + lr)*32 + lc);
    #pragma unroll
    for (int n = 0; n < NFRAG; n++)
      bfr[n] = *(const bf16x8*)(Bs + (wc*(BN/2) + n*16 + lr)*32 + lc);
    #pragma unroll
    for (int m = 0; m < 4; m++)
      #pragma unroll
      for (int n = 0; n < NFRAG; n++)
        acc[m][n] = __builtin_amdgcn_mfma_f32_16x16x32_bf16(af[m], bfr[n], acc[m][n], 0, 0, 0);
    __syncthreads();
  }

  int r0 = (l >> 4) * 4, c0 = l & 15;
  #pragma unroll
  for (int m = 0; m < 4; m++) {
    #pragma unroll
    for (int n = 0; n < NFRAG; n++) {
      size_t row = m0 + wr*64 + m*16 + r0;
      size_t col = n0 + wc*(BN/2) + n*16 + c0;
      float bv = bias[col];
      #pragma unroll
      for (int r = 0; r < 4; r++) {
        float vv = acc[m][n][r] + bv;
        size_t idx = (row + r) * (size_t)N + col;
        if (EPI == 0) {
          ((bf16_t*)outp)[idx] = (bf16_t)vv;
        } else if (EPI == 1) {
          ((float*)outp)[idx] = vv + resid[idx];
        } else {
          ((bf16_t*)outp)[idx] = (bf16_t)gelu_fast(vv);
        }
      }
    }
  }
}

// ---------------- causal flash attention ----------------
// qkv: [4096][3072] bf16, row=(b,s), cols: q=h*64+d, k=1024+h*64+d, v=2048+h*64+d
// out: [4096][1024] bf16 (b,s,h*64+d)
// Block mapping is REVERSED in qt so the longest (qt=31) blocks dispatch first.
__global__ __launch_bounds__(256)
void attn_kernel(const bf16_t* __restrict__ qkv, bf16_t* __restrict__ out) {
  int qt = 31 - (blockIdx.x >> 5);
  int bh = blockIdx.x & 31;
  int b = bh >> 4, h = bh & 15;
  int t = threadIdx.x, w = t >> 6, l = t & 63;

  __shared__ bf16_t Ks[64*64];      // XOR-swizzled [krow][hd]
  __shared__ bf16_t Vt[64*72];      // V^T padded: [d][krow], stride 72
  __shared__ bf16_t Ps[4][16*64];   // per-wave P tile, XOR-swizzled

  const size_t RS = 3 * HDIM;  // 3072
  const bf16_t* qb = qkv + (size_t)b * SEQ * RS + h * HEADD;
  const bf16_t* kb = qb + HDIM;
  const bf16_t* vb = qb + 2 * HDIM;

  int lr = l & 15, lg = l >> 4;

  bf16x8 qf[2];
  {
    size_t qrow = (size_t)qt * 64 + w * 16 + lr;
    qf[0] = *(const bf16x8*)(qb + qrow * RS + lg * 8);
    qf[1] = *(const bf16x8*)(qb + qrow * RS + 32 + lg * 8);
  }

  f32x4 o[4];
  #pragma unroll
  for (int d = 0; d < 4; d++) o[d] = (f32x4)(0.0f);
  float mrow[4], lsum[4];
  #pragma unroll
  for (int r = 0; r < 4; r++) { mrow[r] = -1e30f; lsum[r] = 0.0f; }

  // scale with log2(e) folded in: softmax uses exp2
  const float SCALE = 0.125f * 1.44269504f;

  int srow = t >> 2, sc0 = (t & 3) * 16;
  int nkt = qt + 1;

  const bf16_t* kg0 = kb + (size_t)srow * RS + sc0;
  const bf16_t* vg0 = vb + (size_t)srow * RS + sc0;

  // prefetch regs for tile 0
  bf16x8 kr0 = *(const bf16x8*)kg0;
  bf16x8 kr1 = *(const bf16x8*)(kg0 + 8);
  bf16x8 vr0 = *(const bf16x8*)vg0;
  bf16x8 vr1 = *(const bf16x8*)(vg0 + 8);

  for (int kt = 0; kt < nkt; kt++) {
    { // write staged regs to LDS: K swizzled, V transposed (padded stride 72)
      int ba = srow * 128 + sc0 * 2;
      int sw = (srow & 7) << 4;
      *(bf16x8*)((char*)Ks + ((ba) ^ sw))      = kr0;
      *(bf16x8*)((char*)Ks + ((ba + 16) ^ sw)) = kr1;
      #pragma unroll
      for (int i = 0; i < 8; i++) {
        Vt[(sc0 + i)     * 72 + srow] = vr0[i];
        Vt[(sc0 + 8 + i) * 72 + srow] = vr1[i];
      }
    }
    __syncthreads();

    // issue global loads for tile kt+1 — latency hides under compute below
    if (kt + 1 < nkt) {
      const bf16_t* kg = kg0 + (size_t)(kt + 1) * 64 * RS;
      const bf16_t* vg = vg0 + (size_t)(kt + 1) * 64 * RS;
      kr0 = *(const bf16x8*)kg;
      kr1 = *(const bf16x8*)(kg + 8);
      vr0 = *(const bf16x8*)vg;
      vr1 = *(const bf16x8*)(vg + 8);
    }

    // QK^T
    f32x4 sc[4];
    #pragma unroll
    for (int kt2 = 0; kt2 < 4; kt2++) {
      sc[kt2] = (f32x4)(0.0f);
      #pragma unroll
      for (int kk = 0; kk < 2; kk++) {
        int row = kt2 * 16 + lr;
        int off = (row * 128 + kk * 64 + lg * 16) ^ ((row & 7) << 4);
        bf16x8 kf = *(const bf16x8*)((char*)Ks + off);
        sc[kt2] = __builtin_amdgcn_mfma_f32_16x16x32_bf16(qf[kk], kf, sc[kt2], 0, 0, 0);
      }
    }
    // scale (log2 domain); causal mask only on the diagonal tile
    #pragma unroll
    for (int kt2 = 0; kt2 < 4; kt2++) {
      #pragma unroll
      for (int r = 0; r < 4; r++) sc[kt2][r] *= SCALE;
    }
    if (kt == qt) {
      int qrow0 = qt*64 + w*16 + lg*4;
      #pragma unroll
      for (int kt2 = 0; kt2 < 4; kt2++) {
        int kcol = kt*64 + kt2*16 + lr;
        #pragma unroll
        for (int r = 0; r < 4; r++)
          if (kcol > qrow0 + r) sc[kt2][r] = -1e30f;
      }
    }
    // online softmax (exp2 domain); sum reduction deferred to the end
    float alpha[4];
    #pragma unroll
    for (int r = 0; r < 4; r++) {
      float tm = fmaxf(fmaxf(sc[0][r], sc[1][r]), fmaxf(sc[2][r], sc[3][r]));
      #pragma unroll
      for (int o2 = 1; o2 < 16; o2 <<= 1) tm = fmaxf(tm, __shfl_xor(tm, o2));
      float nm = fmaxf(mrow[r], tm);
      alpha[r] = exp2f(mrow[r] - nm);
      mrow[r] = nm;
    }
    #pragma unroll
    for (int r = 0; r < 4; r++) {
      float p0 = exp2f(sc[0][r] - mrow[r]);
      float p1 = exp2f(sc[1][r] - mrow[r]);
      float p2 = exp2f(sc[2][r] - mrow[r]);
      float p3 = exp2f(sc[3][r] - mrow[r]);
      sc[0][r] = p0; sc[1][r] = p1; sc[2][r] = p2; sc[3][r] = p3;
      lsum[r] = lsum[r] * alpha[r] + (p0 + p1 + p2 + p3);
    }
    #pragma unroll
    for (int d = 0; d < 4; d++)
      #pragma unroll
      for (int r = 0; r < 4; r++) o[d][r] *= alpha[r];

    // P -> LDS (bf16, swizzled), wave-private
    bf16_t* pw = Ps[w];
    #pragma unroll
    for (int kt2 = 0; kt2 < 4; kt2++) {
      #pragma unroll
      for (int r = 0; r < 4; r++) {
        int prow = lg * 4 + r;
        int off = (prow * 128 + (kt2 * 16 + lr) * 2) ^ ((prow & 7) << 4);
        *(bf16_t*)((char*)pw + off) = (bf16_t)sc[kt2][r];
      }
    }
    asm volatile("s_waitcnt lgkmcnt(0)" ::: "memory");
    // PV
    #pragma unroll
    for (int d = 0; d < 4; d++) {
      #pragma unroll
      for (int kk = 0; kk < 2; kk++) {
        int poff = (lr * 128 + kk * 64 + lg * 16) ^ ((lr & 7) << 4);
        bf16x8 pf = *(const bf16x8*)((char*)pw + poff);
        bf16x8 vf = *(const bf16x8*)(Vt + (d*16 + lr) * 72 + kk * 32 + lg * 8);
        o[d] = __builtin_amdgcn_mfma_f32_16x16x32_bf16(pf, vf, o[d], 0, 0, 0);
      }
    }
    __syncthreads();
  }

  // deferred 16-lane sum reduction (once, not per tile)
  #pragma unroll
  for (int r = 0; r < 4; r++) {
    float acc = lsum[r];
    #pragma unroll
    for (int o2 = 1; o2 < 16; o2 <<= 1) acc += __shfl_xor(acc, o2);
    lsum[r] = acc;
  }

  #pragma unroll
  for (int d = 0; d < 4; d++) {
    #pragma unroll
    for (int r = 0; r < 4; r++) {
      size_t qrow = (size_t)qt*64 + w*16 + lg*4 + r;
      out[((size_t)b * SEQ + qrow) * HDIM + h * HEADD + d*16 + lr] =
          (bf16_t)(o[d][r] / lsum[r]);
    }
  }
}

extern "C" void kernel_launch(void* const* d_in, const int* in_sizes, int n_in,
                              void* d_out, int out_size, void* d_ws, size_t ws_size,
                              hipStream_t stream) {
  (void)in_sizes; (void)n_in; (void)out_size; (void)ws_size;
  const float* x     = (const float*)d_in[0];
  const float* w_qkv = (const float*)d_in[1];
  const float* b_qkv = (const float*)d_in[2];
  const float* w_out = (const float*)d_in[3];
  const float* b_out = (const float*)d_in[4];
  const float* ln1_g = (const float*)d_in[5];
  const float* ln1_b = (const float*)d_in[6];
  const float* ln2_g = (const float*)d_in[7];
  const float* ln2_b = (const float*)d_in[8];
  const float* w1    = (const float*)d_in[9];
  const float* b1    = (const float*)d_in[10];
  const float* w2    = (const float*)d_in[11];
  const float* b2    = (const float*)d_in[12];
  float* out = (float*)d_out;

  char* ws = (char*)d_ws;
  size_t off = 0;
  auto alloc = [&](size_t bytes) -> void* {
    void* p = ws + off;
    off += (bytes + 255) & ~(size_t)255;
    return p;
  };
  // total ~88 MB
  bf16_t* wqkvT = (bf16_t*)alloc((size_t)3072*1024*2);
  bf16_t* woutT = (bf16_t*)alloc((size_t)1024*1024*2);
  bf16_t* w1T   = (bf16_t*)alloc((size_t)4096*1024*2);
  bf16_t* w2T   = (bf16_t*)alloc((size_t)1024*4096*2);
  bf16_t* ln1o  = (bf16_t*)alloc((size_t)4096*1024*2);   // reused as h2
  bf16_t* qkvb  = (bf16_t*)alloc((size_t)4096*4096*2);   // qkv (4096x3072), reused as gelu-act (4096x4096)
  bf16_t* attno = (bf16_t*)alloc((size_t)4096*1024*2);
  float*  x2    = (float*) alloc((size_t)4096*1024*4);
  bf16_t* h2 = ln1o;
  bf16_t* g  = qkvb;

  dim3 blk(256);
  transpose_cast<<<dim3(3072/32, 1024/32), blk, 0, stream>>>(w_qkv, wqkvT, 1024, 3072);
  transpose_cast<<<dim3(1024/32, 1024/32), blk, 0, stream>>>(w_out, woutT, 1024, 1024);
  transpose_cast<<<dim3(4096/32, 1024/32), blk, 0, stream>>>(w1,    w1T,   1024, 4096);
  transpose_cast<<<dim3(1024/32, 4096/32), blk, 0, stream>>>(w2,    w2T,   4096, 1024);

  ln_kernel<<<4096, blk, 0, stream>>>(x, ln1_g, ln1_b, ln1o);
  gemm_bt<0,128><<<dim3(24, 32), blk, 0, stream>>>(ln1o, wqkvT, b_qkv, nullptr, qkvb, 4096, 3072, 1024);
  attn_kernel<<<1024, blk, 0, stream>>>(qkvb, attno);
  gemm_bt<1,64><<<dim3(16, 32), blk, 0, stream>>>(attno, woutT, b_out, x, x2, 4096, 1024, 1024);
  ln_kernel<<<4096, blk, 0, stream>>>(x2, ln2_g, ln2_b, h2);
  gemm_bt<2,128><<<dim3(32, 32), blk, 0, stream>>>(h2, w1T, b1, nullptr, g, 4096, 4096, 1024);
  gemm_bt<1,64><<<dim3(16, 32), blk, 0, stream>>>(g, w2T, b2, x2, out, 4096, 1024, 4096);
}

// Round 5
// 290.634 us; speedup vs baseline: 1.2331x; 1.0168x over previous
//
#include <hip/hip_runtime.h>
#include <hip/hip_bf16.h>

typedef __bf16 bf16_t;
typedef __bf16 bf16x8 __attribute__((ext_vector_type(8)));
typedef __bf16 bf16x4 __attribute__((ext_vector_type(4)));
typedef float  f32x4  __attribute__((ext_vector_type(4)));

#define HDIM 1024
#define SEQ  2048
#define NHEAD 16
#define HEADD 64

__device__ __forceinline__ void gld_lds16(const void* g, void* l) {
  __builtin_amdgcn_global_load_lds(
      (const __attribute__((address_space(1))) unsigned int*)g,
      (__attribute__((address_space(3))) unsigned int*)l, 16, 0, 0);
}

// ---------------- LayerNorm(fp32 in) -> bf16 out ----------------
__global__ __launch_bounds__(256) void ln_kernel(const float* __restrict__ x,
                                                 const float* __restrict__ gam,
                                                 const float* __restrict__ bet,
                                                 bf16_t* __restrict__ out) {
  int row = blockIdx.x;
  int t = threadIdx.x;
  const float4* xr = (const float4*)(x + (size_t)row * HDIM);
  float4 v = xr[t];
  float s = v.x + v.y + v.z + v.w;
  float ss = v.x*v.x + v.y*v.y + v.z*v.z + v.w*v.w;
  #pragma unroll
  for (int o = 32; o > 0; o >>= 1) {
    s  += __shfl_xor(s, o);
    ss += __shfl_xor(ss, o);
  }
  __shared__ float red[8];
  int w = t >> 6;
  if ((t & 63) == 0) { red[w*2] = s; red[w*2+1] = ss; }
  __syncthreads();
  s  = red[0] + red[2] + red[4] + red[6];
  ss = red[1] + red[3] + red[5] + red[7];
  float mu  = s * (1.0f / HDIM);
  float var = ss * (1.0f / HDIM) - mu * mu;
  float rstd = rsqrtf(var + 1e-5f);
  float4 g4 = ((const float4*)gam)[t];
  float4 b4 = ((const float4*)bet)[t];
  bf16x4 o4;
  o4[0] = (bf16_t)((v.x - mu) * rstd * g4.x + b4.x);
  o4[1] = (bf16_t)((v.y - mu) * rstd * g4.y + b4.y);
  o4[2] = (bf16_t)((v.z - mu) * rstd * g4.z + b4.z);
  o4[3] = (bf16_t)((v.w - mu) * rstd * g4.w + b4.w);
  *(bf16x4*)(out + (size_t)row * HDIM + t * 4) = o4;
}

// ---------------- W[K][N] fp32 -> W^T[N][K] bf16 ----------------
__global__ __launch_bounds__(256) void transpose_cast(const float* __restrict__ W,
                                                      bf16_t* __restrict__ Wt,
                                                      int Kd, int Nd) {
  __shared__ float tile[32][33];
  int n0 = blockIdx.x * 32, k0 = blockIdx.y * 32;
  int tx = threadIdx.x & 31, ty = threadIdx.x >> 5;
  #pragma unroll
  for (int i = 0; i < 4; i++)
    tile[ty + i*8][tx] = W[(size_t)(k0 + ty + i*8) * Nd + n0 + tx];
  __syncthreads();
  #pragma unroll
  for (int i = 0; i < 4; i++)
    Wt[(size_t)(n0 + ty + i*8) * Kd + k0 + tx] = (bf16_t)tile[tx][ty + i*8];
}

// tanh-form GELU, exp2-based (v_exp_f32 is natively 2^x); ~8 VALU ops
__device__ __forceinline__ float gelu_fast(float x) {
  float y = 0.7978845608f * (x + 0.044715f * x * x * x);
  float u = exp2f(y * 2.885390082f);           // e^(2y)
  float th = 1.0f - 2.0f * __builtin_amdgcn_rcpf(u + 1.0f);
  return 0.5f * x * (1.0f + th);
}

// ---------------- GEMM: C[M][N] = A[M][K](bf16) @ Bt[N][K]^T + bias ----------------
// EPI: 0 = bias, bf16 out; 1 = bias + fp32 residual, fp32 out; 2 = bias + GELU, bf16 out
// BN: 128 (4 n-frags/wave) or 64 (2 n-frags/wave, grid has 2x blocks for small N)
template<int EPI, int BN>
__global__ __launch_bounds__(256, 2)
void gemm_bt(const bf16_t* __restrict__ A, const bf16_t* __restrict__ Bt,
             const float* __restrict__ bias, const float* __restrict__ resid,
             void* __restrict__ outp, int M, int N, int K) {
  constexpr int NFRAG = BN / 32;   // 4 for BN=128, 2 for BN=64
  __shared__ bf16_t As[128*32];
  __shared__ bf16_t Bs[BN*32];
  int t = threadIdx.x;
  int w = t >> 6, l = t & 63;
  int wr = w >> 1, wc = w & 1;
  size_t m0 = (size_t)blockIdx.y * 128, n0 = (size_t)blockIdx.x * BN;

  f32x4 acc[4][NFRAG];
  #pragma unroll
  for (int m = 0; m < 4; m++)
    #pragma unroll
    for (int n = 0; n < NFRAG; n++) acc[m][n] = (f32x4)(0.0f);

  int srow = t >> 2, scol = (t & 3) * 8;
  const bf16_t* ag = A  + (m0 + srow) * K + scol;
  const bf16_t* bg = Bt + (n0 + srow) * K + scol;
  bf16_t* al = As + srow * 32 + scol;
  bf16_t* bl = Bs + srow * 32 + scol;

  int lr = l & 15, lc = (l >> 4) * 8;

  for (int k0 = 0; k0 < K; k0 += 32) {
    gld_lds16(ag + k0, al);
    gld_lds16(ag + k0 + (size_t)64 * K, al + 64*32);
    gld_lds16(bg + k0, bl);
    if constexpr (BN == 128)
      gld_lds16(bg + k0 + (size_t)64 * K, bl + 64*32);
    __syncthreads();
    bf16x8 af[4], bfr[NFRAG];
    #pragma unroll
    for (int m = 0; m < 4; m++)
      af[m] = *(const bf16x8*)(As + (wr*64 + m*16 + lr)*32 + lc);
    #pragma unroll
    for (int n = 0; n < NFRAG; n++)
      bfr[n] = *(const bf16x8*)(Bs + (wc*(BN/2) + n*16 + lr)*32 + lc);
    #pragma unroll
    for (int m = 0; m < 4; m++)
      #pragma unroll
      for (int n = 0; n < NFRAG; n++)
        acc[m][n] = __builtin_amdgcn_mfma_f32_16x16x32_bf16(af[m], bfr[n], acc[m][n], 0, 0, 0);
    __syncthreads();
  }

  int r0 = (l >> 4) * 4, c0 = l & 15;
  #pragma unroll
  for (int m = 0; m < 4; m++) {
    #pragma unroll
    for (int n = 0; n < NFRAG; n++) {
      size_t row = m0 + wr*64 + m*16 + r0;
      size_t col = n0 + wc*(BN/2) + n*16 + c0;
      float bv = bias[col];
      #pragma unroll
      for (int r = 0; r < 4; r++) {
        float vv = acc[m][n][r] + bv;
        size_t idx = (row + r) * (size_t)N + col;
        if (EPI == 0) {
          ((bf16_t*)outp)[idx] = (bf16_t)vv;
        } else if (EPI == 1) {
          ((float*)outp)[idx] = vv + resid[idx];
        } else {
          ((bf16_t*)outp)[idx] = (bf16_t)gelu_fast(vv);
        }
      }
    }
  }
}

// ---------------- causal flash attention ----------------
// qkv: [4096][3072] bf16, row=(b,s), cols: q=h*64+d, k=1024+h*64+d, v=2048+h*64+d
// out: [4096][1024] bf16 (b,s,h*64+d)
// QBLK=128, 8 waves (wave w owns q-rows qt*128 + w*16 + [0,16)).
// Block pairing: blocks i and i+256 have qt summing to 15 so each CU's
// resident pair does equal work (grid 512 = exactly 2 blocks/CU).
__global__ __launch_bounds__(512, 4)
void attn_kernel(const bf16_t* __restrict__ qkv, bf16_t* __restrict__ out) {
  int idx = blockIdx.x;
  int half = idx >> 8;              // 0 or 1
  int sub = idx & 255;
  int qth = sub >> 5;               // 0..7
  int qt = half ? qth : (15 - qth); // first half: 15..8 (long blocks first)
  int bh = sub & 31;
  int b = bh >> 4, h = bh & 15;
  int t = threadIdx.x, w = t >> 6, l = t & 63;

  __shared__ bf16_t Ks[64*64];      // XOR-swizzled [krow][d]
  __shared__ bf16_t Vt[64*72];      // V^T [d][k], stride 72, k-index XOR-swizzled by F(d)
  __shared__ bf16_t Ps[8][16*64];   // per-wave P tile, XOR-swizzled

  const size_t RS = 3 * HDIM;  // 3072
  const bf16_t* qb = qkv + (size_t)b * SEQ * RS + h * HEADD;
  const bf16_t* kb = qb + HDIM;
  const bf16_t* vb = qb + 2 * HDIM;

  int lr = l & 15, lg = l >> 4;

  bf16x8 qf[2];
  {
    size_t qrow = (size_t)qt * 128 + w * 16 + lr;
    qf[0] = *(const bf16x8*)(qb + qrow * RS + lg * 8);
    qf[1] = *(const bf16x8*)(qb + qrow * RS + 32 + lg * 8);
  }

  f32x4 o[4];
  #pragma unroll
  for (int d = 0; d < 4; d++) o[d] = (f32x4)(0.0f);
  float mrow[4], lsum[4];
  #pragma unroll
  for (int r = 0; r < 4; r++) { mrow[r] = -1e30f; lsum[r] = 0.0f; }

  const float SCALE = 0.125f * 1.44269504f;   // 1/sqrt(64) * log2(e)

  // staging assignment: 512 threads, 64 rows x 64 cols, one bf16x8 each
  int srow = t >> 3, scol = (t & 7) * 8;
  int Fv = ((scol >> 3) & 7) << 3;            // V^T k-swizzle for this thread's d-group
  int nkt = 2 * qt + 2;

  const bf16_t* kg0 = kb + (size_t)srow * RS + scol;
  const bf16_t* vg0 = vb + (size_t)srow * RS + scol;

  bf16x8 kr = *(const bf16x8*)kg0;
  bf16x8 vr = *(const bf16x8*)vg0;

  int wrow0 = qt * 128 + w * 16;              // wave's first q-row

  for (int kt = 0; kt < nkt; kt++) {
    { // write staged regs to LDS
      int ba = srow * 128 + scol * 2;
      int sw = (srow & 7) << 4;
      *(bf16x8*)((char*)Ks + (ba ^ sw)) = kr;
      int ksw = srow ^ Fv;
      #pragma unroll
      for (int i = 0; i < 8; i++)
        Vt[(scol + i) * 72 + ksw] = vr[i];
    }
    __syncthreads();

    // issue global loads for tile kt+1 — latency hides under compute below
    if (kt + 1 < nkt) {
      kr = *(const bf16x8*)(kg0 + (size_t)(kt + 1) * 64 * RS);
      vr = *(const bf16x8*)(vg0 + (size_t)(kt + 1) * 64 * RS);
    }

    bool skip = (kt * 64) > (wrow0 + 15);     // this wave entirely above diagonal
    if (!skip) {
      // QK^T
      f32x4 sc[4];
      #pragma unroll
      for (int kt2 = 0; kt2 < 4; kt2++) {
        sc[kt2] = (f32x4)(0.0f);
        #pragma unroll
        for (int kk = 0; kk < 2; kk++) {
          int row = kt2 * 16 + lr;
          int off = (row * 128 + kk * 64 + lg * 16) ^ ((row & 7) << 4);
          bf16x8 kf = *(const bf16x8*)((char*)Ks + off);
          sc[kt2] = __builtin_amdgcn_mfma_f32_16x16x32_bf16(qf[kk], kf, sc[kt2], 0, 0, 0);
        }
      }
      // scale (log2 domain); causal mask only near the diagonal
      #pragma unroll
      for (int kt2 = 0; kt2 < 4; kt2++) {
        #pragma unroll
        for (int r = 0; r < 4; r++) sc[kt2][r] *= SCALE;
      }
      if (kt * 64 + 63 > wrow0) {
        int qrow0 = wrow0 + lg * 4;
        #pragma unroll
        for (int kt2 = 0; kt2 < 4; kt2++) {
          int kcol = kt*64 + kt2*16 + lr;
          #pragma unroll
          for (int r = 0; r < 4; r++)
            if (kcol > qrow0 + r) sc[kt2][r] = -1e30f;
        }
      }
      // online softmax (exp2 domain); 16-lane reduce; sum deferred
      float alpha[4];
      #pragma unroll
      for (int r = 0; r < 4; r++) {
        float tm = fmaxf(fmaxf(sc[0][r], sc[1][r]), fmaxf(sc[2][r], sc[3][r]));
        #pragma unroll
        for (int o2 = 1; o2 < 16; o2 <<= 1) tm = fmaxf(tm, __shfl_xor(tm, o2));
        float nm = fmaxf(mrow[r], tm);
        alpha[r] = exp2f(mrow[r] - nm);
        mrow[r] = nm;
      }
      #pragma unroll
      for (int r = 0; r < 4; r++) {
        float p0 = exp2f(sc[0][r] - mrow[r]);
        float p1 = exp2f(sc[1][r] - mrow[r]);
        float p2 = exp2f(sc[2][r] - mrow[r]);
        float p3 = exp2f(sc[3][r] - mrow[r]);
        sc[0][r] = p0; sc[1][r] = p1; sc[2][r] = p2; sc[3][r] = p3;
        lsum[r] = lsum[r] * alpha[r] + (p0 + p1 + p2 + p3);
      }
      #pragma unroll
      for (int d = 0; d < 4; d++)
        #pragma unroll
        for (int r = 0; r < 4; r++) o[d][r] *= alpha[r];

      // P -> LDS (bf16, swizzled), wave-private
      bf16_t* pw = Ps[w];
      #pragma unroll
      for (int kt2 = 0; kt2 < 4; kt2++) {
        #pragma unroll
        for (int r = 0; r < 4; r++) {
          int prow = lg * 4 + r;
          int off = (prow * 128 + (kt2 * 16 + lr) * 2) ^ ((prow & 7) << 4);
          *(bf16_t*)((char*)pw + off) = (bf16_t)sc[kt2][r];
        }
      }
      asm volatile("s_waitcnt lgkmcnt(0)" ::: "memory");
      // PV (V^T reads carry the k-index swizzle F(d))
      #pragma unroll
      for (int d = 0; d < 4; d++) {
        int vrow = d * 16 + lr;
        int Fd = ((vrow >> 3) & 7) << 3;
        #pragma unroll
        for (int kk = 0; kk < 2; kk++) {
          int poff = (lr * 128 + kk * 64 + lg * 16) ^ ((lr & 7) << 4);
          bf16x8 pf = *(const bf16x8*)((char*)pw + poff);
          bf16x8 vf = *(const bf16x8*)(Vt + vrow * 72 + ((kk * 32 + lg * 8) ^ Fd));
          o[d] = __builtin_amdgcn_mfma_f32_16x16x32_bf16(pf, vf, o[d], 0, 0, 0);
        }
      }
    }
    __syncthreads();
  }

  // deferred 16-lane sum reduction (once, not per tile)
  #pragma unroll
  for (int r = 0; r < 4; r++) {
    float acc = lsum[r];
    #pragma unroll
    for (int o2 = 1; o2 < 16; o2 <<= 1) acc += __shfl_xor(acc, o2);
    lsum[r] = acc;
  }

  #pragma unroll
  for (int d = 0; d < 4; d++) {
    #pragma unroll
    for (int r = 0; r < 4; r++) {
      size_t qrow = (size_t)qt*128 + w*16 + lg*4 + r;
      out[((size_t)b * SEQ + qrow) * HDIM + h * HEADD + d*16 + lr] =
          (bf16_t)(o[d][r] / lsum[r]);
    }
  }
}

extern "C" void kernel_launch(void* const* d_in, const int* in_sizes, int n_in,
                              void* d_out, int out_size, void* d_ws, size_t ws_size,
                              hipStream_t stream) {
  (void)in_sizes; (void)n_in; (void)out_size; (void)ws_size;
  const float* x     = (const float*)d_in[0];
  const float* w_qkv = (const float*)d_in[1];
  const float* b_qkv = (const float*)d_in[2];
  const float* w_out = (const float*)d_in[3];
  const float* b_out = (const float*)d_in[4];
  const float* ln1_g = (const float*)d_in[5];
  const float* ln1_b = (const float*)d_in[6];
  const float* ln2_g = (const float*)d_in[7];
  const float* ln2_b = (const float*)d_in[8];
  const float* w1    = (const float*)d_in[9];
  const float* b1    = (const float*)d_in[10];
  const float* w2    = (const float*)d_in[11];
  const float* b2    = (const float*)d_in[12];
  float* out = (float*)d_out;

  char* ws = (char*)d_ws;
  size_t off = 0;
  auto alloc = [&](size_t bytes) -> void* {
    void* p = ws + off;
    off += (bytes + 255) & ~(size_t)255;
    return p;
  };
  // total ~88 MB
  bf16_t* wqkvT = (bf16_t*)alloc((size_t)3072*1024*2);
  bf16_t* woutT = (bf16_t*)alloc((size_t)1024*1024*2);
  bf16_t* w1T   = (bf16_t*)alloc((size_t)4096*1024*2);
  bf16_t* w2T   = (bf16_t*)alloc((size_t)1024*4096*2);
  bf16_t* ln1o  = (bf16_t*)alloc((size_t)4096*1024*2);   // reused as h2
  bf16_t* qkvb  = (bf16_t*)alloc((size_t)4096*4096*2);   // qkv (4096x3072), reused as gelu-act (4096x4096)
  bf16_t* attno = (bf16_t*)alloc((size_t)4096*1024*2);
  float*  x2    = (float*) alloc((size_t)4096*1024*4);
  bf16_t* h2 = ln1o;
  bf16_t* g  = qkvb;

  dim3 blk(256);
  transpose_cast<<<dim3(3072/32, 1024/32), blk, 0, stream>>>(w_qkv, wqkvT, 1024, 3072);
  transpose_cast<<<dim3(1024/32, 1024/32), blk, 0, stream>>>(w_out, woutT, 1024, 1024);
  transpose_cast<<<dim3(4096/32, 1024/32), blk, 0, stream>>>(w1,    w1T,   1024, 4096);
  transpose_cast<<<dim3(1024/32, 4096/32), blk, 0, stream>>>(w2,    w2T,   4096, 1024);

  ln_kernel<<<4096, blk, 0, stream>>>(x, ln1_g, ln1_b, ln1o);
  gemm_bt<0,128><<<dim3(24, 32), blk, 0, stream>>>(ln1o, wqkvT, b_qkv, nullptr, qkvb, 4096, 3072, 1024);
  attn_kernel<<<512, dim3(512), 0, stream>>>(qkvb, attno);
  gemm_bt<1,64><<<dim3(16, 32), blk, 0, stream>>>(attno, woutT, b_out, x, x2, 4096, 1024, 1024);
  ln_kernel<<<4096, blk, 0, stream>>>(x2, ln2_g, ln2_b, h2);
  gemm_bt<2,128><<<dim3(32, 32), blk, 0, stream>>>(h2, w1T, b1, nullptr, g, 4096, 4096, 1024);
  gemm_bt<1,64><<<dim3(16, 32), blk, 0, stream>>>(g, w2T, b2, x2, out, 4096, 1024, 4096);
}

// Round 6
// 278.622 us; speedup vs baseline: 1.2863x; 1.0431x over previous
//
#include <hip/hip_runtime.h>
#include <hip/hip_bf16.h>

typedef __bf16 bf16_t;
typedef __bf16 bf16x8 __attribute__((ext_vector_type(8)));
typedef __bf16 bf16x4 __attribute__((ext_vector_type(4)));
typedef float  f32x4  __attribute__((ext_vector_type(4)));

#define HDIM 1024
#define SEQ  2048
#define NHEAD 16
#define HEADD 64

__device__ __forceinline__ void gld_lds16(const void* g, void* l) {
  __builtin_amdgcn_global_load_lds(
      (const __attribute__((address_space(1))) unsigned int*)g,
      (__attribute__((address_space(3))) unsigned int*)l, 16, 0, 0);
}

// ---------------- LayerNorm(fp32 in) -> bf16 out ----------------
__global__ __launch_bounds__(256) void ln_kernel(const float* __restrict__ x,
                                                 const float* __restrict__ gam,
                                                 const float* __restrict__ bet,
                                                 bf16_t* __restrict__ out) {
  int row = blockIdx.x;
  int t = threadIdx.x;
  const float4* xr = (const float4*)(x + (size_t)row * HDIM);
  float4 v = xr[t];
  float s = v.x + v.y + v.z + v.w;
  float ss = v.x*v.x + v.y*v.y + v.z*v.z + v.w*v.w;
  #pragma unroll
  for (int o = 32; o > 0; o >>= 1) {
    s  += __shfl_xor(s, o);
    ss += __shfl_xor(ss, o);
  }
  __shared__ float red[8];
  int w = t >> 6;
  if ((t & 63) == 0) { red[w*2] = s; red[w*2+1] = ss; }
  __syncthreads();
  s  = red[0] + red[2] + red[4] + red[6];
  ss = red[1] + red[3] + red[5] + red[7];
  float mu  = s * (1.0f / HDIM);
  float var = ss * (1.0f / HDIM) - mu * mu;
  float rstd = rsqrtf(var + 1e-5f);
  float4 g4 = ((const float4*)gam)[t];
  float4 b4 = ((const float4*)bet)[t];
  bf16x4 o4;
  o4[0] = (bf16_t)((v.x - mu) * rstd * g4.x + b4.x);
  o4[1] = (bf16_t)((v.y - mu) * rstd * g4.y + b4.y);
  o4[2] = (bf16_t)((v.z - mu) * rstd * g4.z + b4.z);
  o4[3] = (bf16_t)((v.w - mu) * rstd * g4.w + b4.w);
  *(bf16x4*)(out + (size_t)row * HDIM + t * 4) = o4;
}

// ---------------- W[K][N] fp32 -> W^T[N][K] bf16 ----------------
__global__ __launch_bounds__(256) void transpose_cast(const float* __restrict__ W,
                                                      bf16_t* __restrict__ Wt,
                                                      int Kd, int Nd) {
  __shared__ float tile[32][33];
  int n0 = blockIdx.x * 32, k0 = blockIdx.y * 32;
  int tx = threadIdx.x & 31, ty = threadIdx.x >> 5;
  #pragma unroll
  for (int i = 0; i < 4; i++)
    tile[ty + i*8][tx] = W[(size_t)(k0 + ty + i*8) * Nd + n0 + tx];
  __syncthreads();
  #pragma unroll
  for (int i = 0; i < 4; i++)
    Wt[(size_t)(n0 + ty + i*8) * Kd + k0 + tx] = (bf16_t)tile[tx][ty + i*8];
}

// tanh-form GELU, exp2-based (v_exp_f32 is natively 2^x); ~8 VALU ops
__device__ __forceinline__ float gelu_fast(float x) {
  float y = 0.7978845608f * (x + 0.044715f * x * x * x);
  float u = exp2f(y * 2.885390082f);           // e^(2y)
  float th = 1.0f - 2.0f * __builtin_amdgcn_rcpf(u + 1.0f);
  return 0.5f * x * (1.0f + th);
}

// ---------------- GEMM: C[M][N] = A[M][K](bf16) @ Bt[N][K]^T + bias ----------------
// EPI: 0 = bias, bf16 out; 1 = bias + fp32 residual, fp32 out; 2 = bias + GELU, bf16 out
// BN: 128 or 64. Double-buffered LDS with prefetch-before-compute (T3-minimum),
// one barrier per K-step. XCD-aware block swizzle: each XCD owns contiguous
// m-rows so A-panels are fetched by a single XCD's L2 (grids all %8 == 0).
template<int EPI, int BN>
__global__ __launch_bounds__(256, 2)
void gemm_bt(const bf16_t* __restrict__ A, const bf16_t* __restrict__ Bt,
             const float* __restrict__ bias, const float* __restrict__ resid,
             void* __restrict__ outp, int M, int N, int K) {
  constexpr int NFRAG = BN / 32;   // 4 for BN=128, 2 for BN=64
  __shared__ bf16_t As[2][128*32];
  __shared__ bf16_t Bs[2][BN*32];
  int t = threadIdx.x;
  int w = t >> 6, l = t & 63;
  int wr = w >> 1, wc = w & 1;

  // XCD swizzle: linear bid -> m-major order, chunked per XCD
  int nbx = gridDim.x;
  int bid = blockIdx.y * nbx + blockIdx.x;
  int chunk = (nbx * gridDim.y) >> 3;
  int nb = (bid & 7) * chunk + (bid >> 3);
  int bm = nb / nbx, bn = nb % nbx;
  size_t m0 = (size_t)bm * 128, n0 = (size_t)bn * BN;

  f32x4 acc[4][NFRAG];
  #pragma unroll
  for (int m = 0; m < 4; m++)
    #pragma unroll
    for (int n = 0; n < NFRAG; n++) acc[m][n] = (f32x4)(0.0f);

  int srow = t >> 2, scol = (t & 3) * 8;
  int soff = srow * 32 + scol;
  const bf16_t* ag = A  + (m0 + srow) * K + scol;
  const bf16_t* bg = Bt + (n0 + srow) * K + scol;

  int lr = l & 15, lc = (l >> 4) * 8;

  auto stage = [&](int buf, int k0) {
    gld_lds16(ag + k0, &As[buf][soff]);
    gld_lds16(ag + k0 + (size_t)64 * K, &As[buf][soff + 64*32]);
    gld_lds16(bg + k0, &Bs[buf][soff]);
    if constexpr (BN == 128)
      gld_lds16(bg + k0 + (size_t)64 * K, &Bs[buf][soff + 64*32]);
  };

  stage(0, 0);
  __syncthreads();
  int cur = 0;
  for (int k0 = 0; k0 < K; k0 += 32) {
    if (k0 + 32 < K) stage(cur ^ 1, k0 + 32);   // prefetch next tile first
    bf16x8 af[4], bfr[NFRAG];
    #pragma unroll
    for (int m = 0; m < 4; m++)
      af[m] = *(const bf16x8*)(&As[cur][(wr*64 + m*16 + lr)*32 + lc]);
    #pragma unroll
    for (int n = 0; n < NFRAG; n++)
      bfr[n] = *(const bf16x8*)(&Bs[cur][(wc*(BN/2) + n*16 + lr)*32 + lc]);
    #pragma unroll
    for (int m = 0; m < 4; m++)
      #pragma unroll
      for (int n = 0; n < NFRAG; n++)
        acc[m][n] = __builtin_amdgcn_mfma_f32_16x16x32_bf16(af[m], bfr[n], acc[m][n], 0, 0, 0);
    __syncthreads();                             // one barrier per K-step
    cur ^= 1;
  }

  int r0 = (l >> 4) * 4, c0 = l & 15;
  #pragma unroll
  for (int m = 0; m < 4; m++) {
    #pragma unroll
    for (int n = 0; n < NFRAG; n++) {
      size_t row = m0 + wr*64 + m*16 + r0;
      size_t col = n0 + wc*(BN/2) + n*16 + c0;
      float bv = bias[col];
      #pragma unroll
      for (int r = 0; r < 4; r++) {
        float vv = acc[m][n][r] + bv;
        size_t idx = (row + r) * (size_t)N + col;
        if (EPI == 0) {
          ((bf16_t*)outp)[idx] = (bf16_t)vv;
        } else if (EPI == 1) {
          ((float*)outp)[idx] = vv + resid[idx];
        } else {
          ((bf16_t*)outp)[idx] = (bf16_t)gelu_fast(vv);
        }
      }
    }
  }
}

// ---------------- causal flash attention ----------------
// qkv: [4096][3072] bf16, row=(b,s), cols: q=h*64+d, k=1024+h*64+d, v=2048+h*64+d
// out: [4096][1024] bf16 (b,s,h*64+d)
// QBLK=128, 8 waves (wave w owns q-rows qt*128 + w*16 + [0,16)).
// Block pairing: blocks i and i+256 have qt summing to 15 so each CU's
// resident pair does equal work (grid 512 = exactly 2 blocks/CU).
__global__ __launch_bounds__(512, 4)
void attn_kernel(const bf16_t* __restrict__ qkv, bf16_t* __restrict__ out) {
  int idx = blockIdx.x;
  int half = idx >> 8;              // 0 or 1
  int sub = idx & 255;
  int qth = sub >> 5;               // 0..7
  int qt = half ? qth : (15 - qth); // first half: 15..8 (long blocks first)
  int bh = sub & 31;
  int b = bh >> 4, h = bh & 15;
  int t = threadIdx.x, w = t >> 6, l = t & 63;

  __shared__ bf16_t Ks[64*64];      // XOR-swizzled [krow][d]
  __shared__ bf16_t Vt[64*72];      // V^T [d][k], stride 72, k-index XOR-swizzled by F(d)
  __shared__ bf16_t Ps[8][16*64];   // per-wave P tile, XOR-swizzled

  const size_t RS = 3 * HDIM;  // 3072
  const bf16_t* qb = qkv + (size_t)b * SEQ * RS + h * HEADD;
  const bf16_t* kb = qb + HDIM;
  const bf16_t* vb = qb + 2 * HDIM;

  int lr = l & 15, lg = l >> 4;

  bf16x8 qf[2];
  {
    size_t qrow = (size_t)qt * 128 + w * 16 + lr;
    qf[0] = *(const bf16x8*)(qb + qrow * RS + lg * 8);
    qf[1] = *(const bf16x8*)(qb + qrow * RS + 32 + lg * 8);
  }

  f32x4 o[4];
  #pragma unroll
  for (int d = 0; d < 4; d++) o[d] = (f32x4)(0.0f);
  float mrow[4], lsum[4];
  #pragma unroll
  for (int r = 0; r < 4; r++) { mrow[r] = -1e30f; lsum[r] = 0.0f; }

  const float SCALE = 0.125f * 1.44269504f;   // 1/sqrt(64) * log2(e)

  // staging assignment: 512 threads, 64 rows x 64 cols, one bf16x8 each
  int srow = t >> 3, scol = (t & 7) * 8;
  int Fv = ((scol >> 3) & 7) << 3;            // V^T k-swizzle for this thread's d-group
  int nkt = 2 * qt + 2;

  const bf16_t* kg0 = kb + (size_t)srow * RS + scol;
  const bf16_t* vg0 = vb + (size_t)srow * RS + scol;

  bf16x8 kr = *(const bf16x8*)kg0;
  bf16x8 vr = *(const bf16x8*)vg0;

  int wrow0 = qt * 128 + w * 16;              // wave's first q-row

  for (int kt = 0; kt < nkt; kt++) {
    { // write staged regs to LDS
      int ba = srow * 128 + scol * 2;
      int sw = (srow & 7) << 4;
      *(bf16x8*)((char*)Ks + (ba ^ sw)) = kr;
      int ksw = srow ^ Fv;
      #pragma unroll
      for (int i = 0; i < 8; i++)
        Vt[(scol + i) * 72 + ksw] = vr[i];
    }
    __syncthreads();

    // issue global loads for tile kt+1 — latency hides under compute below
    if (kt + 1 < nkt) {
      kr = *(const bf16x8*)(kg0 + (size_t)(kt + 1) * 64 * RS);
      vr = *(const bf16x8*)(vg0 + (size_t)(kt + 1) * 64 * RS);
    }

    bool skip = (kt * 64) > (wrow0 + 15);     // this wave entirely above diagonal
    if (!skip) {
      // QK^T
      f32x4 sc[4];
      #pragma unroll
      for (int kt2 = 0; kt2 < 4; kt2++) {
        sc[kt2] = (f32x4)(0.0f);
        #pragma unroll
        for (int kk = 0; kk < 2; kk++) {
          int row = kt2 * 16 + lr;
          int off = (row * 128 + kk * 64 + lg * 16) ^ ((row & 7) << 4);
          bf16x8 kf = *(const bf16x8*)((char*)Ks + off);
          sc[kt2] = __builtin_amdgcn_mfma_f32_16x16x32_bf16(qf[kk], kf, sc[kt2], 0, 0, 0);
        }
      }
      // scale (log2 domain); causal mask only near the diagonal
      #pragma unroll
      for (int kt2 = 0; kt2 < 4; kt2++) {
        #pragma unroll
        for (int r = 0; r < 4; r++) sc[kt2][r] *= SCALE;
      }
      if (kt * 64 + 63 > wrow0) {
        int qrow0 = wrow0 + lg * 4;
        #pragma unroll
        for (int kt2 = 0; kt2 < 4; kt2++) {
          int kcol = kt*64 + kt2*16 + lr;
          #pragma unroll
          for (int r = 0; r < 4; r++)
            if (kcol > qrow0 + r) sc[kt2][r] = -1e30f;
        }
      }
      // online softmax (exp2 domain); 16-lane reduce; sum deferred
      float alpha[4];
      #pragma unroll
      for (int r = 0; r < 4; r++) {
        float tm = fmaxf(fmaxf(sc[0][r], sc[1][r]), fmaxf(sc[2][r], sc[3][r]));
        #pragma unroll
        for (int o2 = 1; o2 < 16; o2 <<= 1) tm = fmaxf(tm, __shfl_xor(tm, o2));
        float nm = fmaxf(mrow[r], tm);
        alpha[r] = exp2f(mrow[r] - nm);
        mrow[r] = nm;
      }
      #pragma unroll
      for (int r = 0; r < 4; r++) {
        float p0 = exp2f(sc[0][r] - mrow[r]);
        float p1 = exp2f(sc[1][r] - mrow[r]);
        float p2 = exp2f(sc[2][r] - mrow[r]);
        float p3 = exp2f(sc[3][r] - mrow[r]);
        sc[0][r] = p0; sc[1][r] = p1; sc[2][r] = p2; sc[3][r] = p3;
        lsum[r] = lsum[r] * alpha[r] + (p0 + p1 + p2 + p3);
      }
      #pragma unroll
      for (int d = 0; d < 4; d++)
        #pragma unroll
        for (int r = 0; r < 4; r++) o[d][r] *= alpha[r];

      // P -> LDS (bf16, swizzled), wave-private
      bf16_t* pw = Ps[w];
      #pragma unroll
      for (int kt2 = 0; kt2 < 4; kt2++) {
        #pragma unroll
        for (int r = 0; r < 4; r++) {
          int prow = lg * 4 + r;
          int off = (prow * 128 + (kt2 * 16 + lr) * 2) ^ ((prow & 7) << 4);
          *(bf16_t*)((char*)pw + off) = (bf16_t)sc[kt2][r];
        }
      }
      asm volatile("s_waitcnt lgkmcnt(0)" ::: "memory");
      // PV (V^T reads carry the k-index swizzle F(d))
      #pragma unroll
      for (int d = 0; d < 4; d++) {
        int vrow = d * 16 + lr;
        int Fd = ((vrow >> 3) & 7) << 3;
        #pragma unroll
        for (int kk = 0; kk < 2; kk++) {
          int poff = (lr * 128 + kk * 64 + lg * 16) ^ ((lr & 7) << 4);
          bf16x8 pf = *(const bf16x8*)((char*)pw + poff);
          bf16x8 vf = *(const bf16x8*)(Vt + vrow * 72 + ((kk * 32 + lg * 8) ^ Fd));
          o[d] = __builtin_amdgcn_mfma_f32_16x16x32_bf16(pf, vf, o[d], 0, 0, 0);
        }
      }
    }
    __syncthreads();
  }

  // deferred 16-lane sum reduction (once, not per tile)
  #pragma unroll
  for (int r = 0; r < 4; r++) {
    float acc = lsum[r];
    #pragma unroll
    for (int o2 = 1; o2 < 16; o2 <<= 1) acc += __shfl_xor(acc, o2);
    lsum[r] = acc;
  }

  #pragma unroll
  for (int d = 0; d < 4; d++) {
    #pragma unroll
    for (int r = 0; r < 4; r++) {
      size_t qrow = (size_t)qt*128 + w*16 + lg*4 + r;
      out[((size_t)b * SEQ + qrow) * HDIM + h * HEADD + d*16 + lr] =
          (bf16_t)(o[d][r] / lsum[r]);
    }
  }
}

extern "C" void kernel_launch(void* const* d_in, const int* in_sizes, int n_in,
                              void* d_out, int out_size, void* d_ws, size_t ws_size,
                              hipStream_t stream) {
  (void)in_sizes; (void)n_in; (void)out_size; (void)ws_size;
  const float* x     = (const float*)d_in[0];
  const float* w_qkv = (const float*)d_in[1];
  const float* b_qkv = (const float*)d_in[2];
  const float* w_out = (const float*)d_in[3];
  const float* b_out = (const float*)d_in[4];
  const float* ln1_g = (const float*)d_in[5];
  const float* ln1_b = (const float*)d_in[6];
  const float* ln2_g = (const float*)d_in[7];
  const float* ln2_b = (const float*)d_in[8];
  const float* w1    = (const float*)d_in[9];
  const float* b1    = (const float*)d_in[10];
  const float* w2    = (const float*)d_in[11];
  const float* b2    = (const float*)d_in[12];
  float* out = (float*)d_out;

  char* ws = (char*)d_ws;
  size_t off = 0;
  auto alloc = [&](size_t bytes) -> void* {
    void* p = ws + off;
    off += (bytes + 255) & ~(size_t)255;
    return p;
  };
  // total ~88 MB
  bf16_t* wqkvT = (bf16_t*)alloc((size_t)3072*1024*2);
  bf16_t* woutT = (bf16_t*)alloc((size_t)1024*1024*2);
  bf16_t* w1T   = (bf16_t*)alloc((size_t)4096*1024*2);
  bf16_t* w2T   = (bf16_t*)alloc((size_t)1024*4096*2);
  bf16_t* ln1o  = (bf16_t*)alloc((size_t)4096*1024*2);   // reused as h2
  bf16_t* qkvb  = (bf16_t*)alloc((size_t)4096*4096*2);   // qkv (4096x3072), reused as gelu-act (4096x4096)
  bf16_t* attno = (bf16_t*)alloc((size_t)4096*1024*2);
  float*  x2    = (float*) alloc((size_t)4096*1024*4);
  bf16_t* h2 = ln1o;
  bf16_t* g  = qkvb;

  dim3 blk(256);
  transpose_cast<<<dim3(3072/32, 1024/32), blk, 0, stream>>>(w_qkv, wqkvT, 1024, 3072);
  transpose_cast<<<dim3(1024/32, 1024/32), blk, 0, stream>>>(w_out, woutT, 1024, 1024);
  transpose_cast<<<dim3(4096/32, 1024/32), blk, 0, stream>>>(w1,    w1T,   1024, 4096);
  transpose_cast<<<dim3(1024/32, 4096/32), blk, 0, stream>>>(w2,    w2T,   4096, 1024);

  ln_kernel<<<4096, blk, 0, stream>>>(x, ln1_g, ln1_b, ln1o);
  gemm_bt<0,128><<<dim3(24, 32), blk, 0, stream>>>(ln1o, wqkvT, b_qkv, nullptr, qkvb, 4096, 3072, 1024);
  attn_kernel<<<512, dim3(512), 0, stream>>>(qkvb, attno);
  gemm_bt<1,64><<<dim3(16, 32), blk, 0, stream>>>(attno, woutT, b_out, x, x2, 4096, 1024, 1024);
  ln_kernel<<<4096, blk, 0, stream>>>(x2, ln2_g, ln2_b, h2);
  gemm_bt<2,128><<<dim3(32, 32), blk, 0, stream>>>(h2, w1T, b1, nullptr, g, 4096, 4096, 1024);
  gemm_bt<1,64><<<dim3(16, 32), blk, 0, stream>>>(g, w2T, b2, x2, out, 4096, 1024, 4096);
}

// Round 7
// 252.554 us; speedup vs baseline: 1.4190x; 1.1032x over previous
//
#include <hip/hip_runtime.h>
#include <hip/hip_bf16.h>

typedef __bf16 bf16_t;
typedef __bf16 bf16x8 __attribute__((ext_vector_type(8)));
typedef __bf16 bf16x4 __attribute__((ext_vector_type(4)));
typedef __bf16 bf16x2 __attribute__((ext_vector_type(2)));
typedef float  f32x4  __attribute__((ext_vector_type(4)));

#define HDIM 1024
#define SEQ  2048
#define NHEAD 16
#define HEADD 64

__device__ __forceinline__ void gld_lds16(const void* g, void* l) {
  __builtin_amdgcn_global_load_lds(
      (const __attribute__((address_space(1))) unsigned int*)g,
      (__attribute__((address_space(3))) unsigned int*)l, 16, 0, 0);
}

// ---------------- LayerNorm(fp32 in) -> bf16 out ----------------
__global__ __launch_bounds__(256) void ln_kernel(const float* __restrict__ x,
                                                 const float* __restrict__ gam,
                                                 const float* __restrict__ bet,
                                                 bf16_t* __restrict__ out) {
  int row = blockIdx.x;
  int t = threadIdx.x;
  const float4* xr = (const float4*)(x + (size_t)row * HDIM);
  float4 v = xr[t];
  float s = v.x + v.y + v.z + v.w;
  float ss = v.x*v.x + v.y*v.y + v.z*v.z + v.w*v.w;
  #pragma unroll
  for (int o = 32; o > 0; o >>= 1) {
    s  += __shfl_xor(s, o);
    ss += __shfl_xor(ss, o);
  }
  __shared__ float red[8];
  int w = t >> 6;
  if ((t & 63) == 0) { red[w*2] = s; red[w*2+1] = ss; }
  __syncthreads();
  s  = red[0] + red[2] + red[4] + red[6];
  ss = red[1] + red[3] + red[5] + red[7];
  float mu  = s * (1.0f / HDIM);
  float var = ss * (1.0f / HDIM) - mu * mu;
  float rstd = rsqrtf(var + 1e-5f);
  float4 g4 = ((const float4*)gam)[t];
  float4 b4 = ((const float4*)bet)[t];
  bf16x4 o4;
  o4[0] = (bf16_t)((v.x - mu) * rstd * g4.x + b4.x);
  o4[1] = (bf16_t)((v.y - mu) * rstd * g4.y + b4.y);
  o4[2] = (bf16_t)((v.z - mu) * rstd * g4.z + b4.z);
  o4[3] = (bf16_t)((v.w - mu) * rstd * g4.w + b4.w);
  *(bf16x4*)(out + (size_t)row * HDIM + t * 4) = o4;
}

// ---------------- W[K][N] fp32 -> W^T[N][K] bf16 ----------------
__global__ __launch_bounds__(256) void transpose_cast(const float* __restrict__ W,
                                                      bf16_t* __restrict__ Wt,
                                                      int Kd, int Nd) {
  __shared__ float tile[32][33];
  int n0 = blockIdx.x * 32, k0 = blockIdx.y * 32;
  int tx = threadIdx.x & 31, ty = threadIdx.x >> 5;
  #pragma unroll
  for (int i = 0; i < 4; i++)
    tile[ty + i*8][tx] = W[(size_t)(k0 + ty + i*8) * Nd + n0 + tx];
  __syncthreads();
  #pragma unroll
  for (int i = 0; i < 4; i++)
    Wt[(size_t)(n0 + ty + i*8) * Kd + k0 + tx] = (bf16_t)tile[tx][ty + i*8];
}

// tanh-form GELU, exp2-based (v_exp_f32 is natively 2^x); ~8 VALU ops
__device__ __forceinline__ float gelu_fast(float x) {
  float y = 0.7978845608f * (x + 0.044715f * x * x * x);
  float u = exp2f(y * 2.885390082f);           // e^(2y)
  float th = 1.0f - 2.0f * __builtin_amdgcn_rcpf(u + 1.0f);
  return 0.5f * x * (1.0f + th);
}

// ---------------- GEMM: C[M][N] = A[M][K](bf16) @ Bt[N][K]^T + bias ----------------
// EPI: 0 = bias, bf16 out; 1 = bias + fp32 residual, fp32 out; 2 = bias + GELU, bf16 out
// BN: 128 or 64. Double-buffered LDS with prefetch-before-compute (T3-minimum),
// one barrier per K-step. XCD-aware block swizzle.
template<int EPI, int BN>
__global__ __launch_bounds__(256, 2)
void gemm_bt(const bf16_t* __restrict__ A, const bf16_t* __restrict__ Bt,
             const float* __restrict__ bias, const float* __restrict__ resid,
             void* __restrict__ outp, int M, int N, int K) {
  constexpr int NFRAG = BN / 32;   // 4 for BN=128, 2 for BN=64
  __shared__ bf16_t As[2][128*32];
  __shared__ bf16_t Bs[2][BN*32];
  int t = threadIdx.x;
  int w = t >> 6, l = t & 63;
  int wr = w >> 1, wc = w & 1;

  // XCD swizzle: linear bid -> m-major order, chunked per XCD
  int nbx = gridDim.x;
  int bid = blockIdx.y * nbx + blockIdx.x;
  int chunk = (nbx * gridDim.y) >> 3;
  int nb = (bid & 7) * chunk + (bid >> 3);
  int bm = nb / nbx, bn = nb % nbx;
  size_t m0 = (size_t)bm * 128, n0 = (size_t)bn * BN;

  f32x4 acc[4][NFRAG];
  #pragma unroll
  for (int m = 0; m < 4; m++)
    #pragma unroll
    for (int n = 0; n < NFRAG; n++) acc[m][n] = (f32x4)(0.0f);

  int srow = t >> 2, scol = (t & 3) * 8;
  int soff = srow * 32 + scol;
  const bf16_t* ag = A  + (m0 + srow) * K + scol;
  const bf16_t* bg = Bt + (n0 + srow) * K + scol;

  int lr = l & 15, lc = (l >> 4) * 8;

  auto stage = [&](int buf, int k0) {
    gld_lds16(ag + k0, &As[buf][soff]);
    gld_lds16(ag + k0 + (size_t)64 * K, &As[buf][soff + 64*32]);
    gld_lds16(bg + k0, &Bs[buf][soff]);
    if constexpr (BN == 128)
      gld_lds16(bg + k0 + (size_t)64 * K, &Bs[buf][soff + 64*32]);
  };

  stage(0, 0);
  __syncthreads();
  int cur = 0;
  for (int k0 = 0; k0 < K; k0 += 32) {
    if (k0 + 32 < K) stage(cur ^ 1, k0 + 32);   // prefetch next tile first
    bf16x8 af[4], bfr[NFRAG];
    #pragma unroll
    for (int m = 0; m < 4; m++)
      af[m] = *(const bf16x8*)(&As[cur][(wr*64 + m*16 + lr)*32 + lc]);
    #pragma unroll
    for (int n = 0; n < NFRAG; n++)
      bfr[n] = *(const bf16x8*)(&Bs[cur][(wc*(BN/2) + n*16 + lr)*32 + lc]);
    #pragma unroll
    for (int m = 0; m < 4; m++)
      #pragma unroll
      for (int n = 0; n < NFRAG; n++)
        acc[m][n] = __builtin_amdgcn_mfma_f32_16x16x32_bf16(af[m], bfr[n], acc[m][n], 0, 0, 0);
    __syncthreads();                             // one barrier per K-step
    cur ^= 1;
  }

  int r0 = (l >> 4) * 4, c0 = l & 15;
  #pragma unroll
  for (int m = 0; m < 4; m++) {
    #pragma unroll
    for (int n = 0; n < NFRAG; n++) {
      size_t row = m0 + wr*64 + m*16 + r0;
      size_t col = n0 + wc*(BN/2) + n*16 + c0;
      float bv = bias[col];
      #pragma unroll
      for (int r = 0; r < 4; r++) {
        float vv = acc[m][n][r] + bv;
        size_t idx = (row + r) * (size_t)N + col;
        if (EPI == 0) {
          ((bf16_t*)outp)[idx] = (bf16_t)vv;
        } else if (EPI == 1) {
          ((float*)outp)[idx] = vv + resid[idx];
        } else {
          ((bf16_t*)outp)[idx] = (bf16_t)gelu_fast(vv);
        }
      }
    }
  }
}

// ---------------- causal flash attention (swapped-QK^T, per-lane-row softmax) ----
// qkv: [4096][3072] bf16, row=(b,s), cols: q=h*64+d, k=1024+h*64+d, v=2048+h*64+d
// out: [4096][1024] bf16 (b,s,h*64+d)
// QBLK=128, 8 waves. Swapped QK^T: S^T = mfma(A=K, B=Q) puts q-row = lane&15,
// k = kt2*16 + (lane>>4)*4 + reg. Softmax per-lane scalar (m, lsum); row reduce
// = in-lane tree + shfl_xor(16,32). P packed bf16x2 -> swizzled LDS (8 b32
// writes, 2 b128 reads). PV = mfma(A=V^T, B=P) -> D[row=d][col=q].
// K/V LDS double-buffered: ONE barrier per tile. Defer-max THR=8 (log2 dom).
__global__ __launch_bounds__(512, 4)
void attn_kernel(const bf16_t* __restrict__ qkv, bf16_t* __restrict__ out) {
  int idx = blockIdx.x;
  int half = idx >> 8;              // 0 or 1
  int sub = idx & 255;
  int qth = sub >> 5;               // 0..7
  int qt = half ? qth : (15 - qth); // first half: 15..8 (long blocks first)
  int bh = sub & 31;
  int b = bh >> 4, h = bh & 15;
  int t = threadIdx.x, w = t >> 6, l = t & 63;

  __shared__ bf16_t Ks[2][64*64];   // XOR-swizzled [krow][d], double-buffered
  __shared__ bf16_t Vt[2][64*72];   // V^T [d][k] stride 72, k XOR-swizzled by F(d)
  __shared__ bf16_t Ps[8][16*64];   // per-wave P tile [q][k], XOR-swizzled

  const size_t RS = 3 * HDIM;  // 3072
  const bf16_t* qb = qkv + (size_t)b * SEQ * RS + h * HEADD;
  const bf16_t* kb = qb + HDIM;
  const bf16_t* vb = qb + 2 * HDIM;

  int lr = l & 15, lg = l >> 4;
  const float SCALE = 0.125f * 1.44269504f;   // 1/sqrt(64) * log2(e), folded into Q

  bf16x8 qf[2];
  {
    size_t qrow = (size_t)qt * 128 + w * 16 + lr;
    qf[0] = *(const bf16x8*)(qb + qrow * RS + lg * 8);
    qf[1] = *(const bf16x8*)(qb + qrow * RS + 32 + lg * 8);
    #pragma unroll
    for (int i = 0; i < 8; i++) {
      qf[0][i] = (bf16_t)((float)qf[0][i] * SCALE);
      qf[1][i] = (bf16_t)((float)qf[1][i] * SCALE);
    }
  }

  f32x4 o[4];
  #pragma unroll
  for (int d = 0; d < 4; d++) o[d] = (f32x4)(0.0f);
  float m = -1e30f, lsum = 0.0f;

  // staging assignment: 512 threads, 64 rows x 64 cols, one bf16x8 each
  int srow = t >> 3, scol = (t & 7) * 8;
  int Fv = ((scol >> 3) & 7) << 3;            // V^T k-swizzle for this thread's d-group
  int nkt = 2 * qt + 2;

  const bf16_t* kg0 = kb + (size_t)srow * RS + scol;
  const bf16_t* vg0 = vb + (size_t)srow * RS + scol;

  bf16x8 kr = *(const bf16x8*)kg0;
  bf16x8 vr = *(const bf16x8*)vg0;

  int wrow0 = qt * 128 + w * 16;              // wave's first q-row
  int qg = wrow0 + lr;                        // this lane's q-row (global)
  bf16_t* pw = Ps[w];
  int psw = (lr & 7) << 4;                    // P swizzle for this lane's row
  int cur = 0;

  for (int kt = 0; kt < nkt; kt++) {
    { // stage tile kt into LDS[cur]
      int ba = srow * 128 + scol * 2;
      int sw = (srow & 7) << 4;
      *(bf16x8*)((char*)Ks[cur] + (ba ^ sw)) = kr;
      int ksw = srow ^ Fv;
      bf16_t* vt = Vt[cur];
      #pragma unroll
      for (int i = 0; i < 8; i++)
        vt[(scol + i) * 72 + ksw] = vr[i];
    }
    // issue global loads for tile kt+1 — arrive during barrier+compute
    if (kt + 1 < nkt) {
      kr = *(const bf16x8*)(kg0 + (size_t)(kt + 1) * 64 * RS);
      vr = *(const bf16x8*)(vg0 + (size_t)(kt + 1) * 64 * RS);
    }
    __syncthreads();   // single barrier: cur written; cur^1 free (all read it last tile)

    bool skipw = (kt * 64) > (wrow0 + 15);    // wave entirely above diagonal
    if (!skipw) {
      // S^T: lane holds S[q=lr][k = kt*64 + kt2*16 + lg*4 + r]
      f32x4 sc[4];
      #pragma unroll
      for (int kt2 = 0; kt2 < 4; kt2++) {
        sc[kt2] = (f32x4)(0.0f);
        #pragma unroll
        for (int kk = 0; kk < 2; kk++) {
          int row = kt2 * 16 + lr;
          int off = (row * 128 + kk * 64 + lg * 16) ^ ((row & 7) << 4);
          bf16x8 kf = *(const bf16x8*)((char*)Ks[cur] + off);
          sc[kt2] = __builtin_amdgcn_mfma_f32_16x16x32_bf16(kf, qf[kk], sc[kt2], 0, 0, 0);
        }
      }
      // causal mask (diagonal region only)
      if (kt * 64 + 63 > wrow0) {
        #pragma unroll
        for (int kt2 = 0; kt2 < 4; kt2++) {
          #pragma unroll
          for (int r = 0; r < 4; r++) {
            int kcol = kt*64 + kt2*16 + lg*4 + r;
            if (kcol > qg) sc[kt2][r] = -1e30f;
          }
        }
      }
      // row max: in-lane tree + 2 cross-group shuffles
      float tm0 = fmaxf(fmaxf(sc[0][0], sc[0][1]), fmaxf(sc[0][2], sc[0][3]));
      float tm1 = fmaxf(fmaxf(sc[1][0], sc[1][1]), fmaxf(sc[1][2], sc[1][3]));
      float tm2 = fmaxf(fmaxf(sc[2][0], sc[2][1]), fmaxf(sc[2][2], sc[2][3]));
      float tm3 = fmaxf(fmaxf(sc[3][0], sc[3][1]), fmaxf(sc[3][2], sc[3][3]));
      float tm = fmaxf(fmaxf(tm0, tm1), fmaxf(tm2, tm3));
      tm = fmaxf(tm, __shfl_xor(tm, 16));
      tm = fmaxf(tm, __shfl_xor(tm, 32));
      // defer-max: only rescale when some row's max grew past THR=8 (log2 domain)
      if (!__all(tm <= m + 8.0f)) {
        float nm = fmaxf(m, tm);
        float alpha = exp2f(m - nm);
        m = nm;
        lsum *= alpha;
        #pragma unroll
        for (int d = 0; d < 4; d++)
          #pragma unroll
          for (int r = 0; r < 4; r++) o[d][r] *= alpha;
      }
      // P = exp2(S - m); pack bf16x2 pairs -> swizzled LDS (8 b32 writes)
      #pragma unroll
      for (int kt2 = 0; kt2 < 4; kt2++) {
        float p0 = exp2f(sc[kt2][0] - m);
        float p1 = exp2f(sc[kt2][1] - m);
        float p2 = exp2f(sc[kt2][2] - m);
        float p3 = exp2f(sc[kt2][3] - m);
        lsum += (p0 + p1) + (p2 + p3);
        bf16x2 pa; pa[0] = (bf16_t)p0; pa[1] = (bf16_t)p1;
        bf16x2 pb; pb[0] = (bf16_t)p2; pb[1] = (bf16_t)p3;
        int base = lr * 128 + kt2 * 32 + lg * 8;
        *(bf16x2*)((char*)pw + ((base)     ^ psw)) = pa;
        *(bf16x2*)((char*)pw + ((base + 4) ^ psw)) = pb;
      }
      asm volatile("s_waitcnt lgkmcnt(0)" ::: "memory");
      // PV: o[dblk] = mfma(A = V^T frag, B = P frag) -> D[row=d][col=q]
      #pragma unroll
      for (int kk = 0; kk < 2; kk++) {
        int poff = (lr * 128 + kk * 64 + lg * 16) ^ psw;
        bf16x8 pf = *(const bf16x8*)((char*)pw + poff);
        #pragma unroll
        for (int dblk = 0; dblk < 4; dblk++) {
          int vrow = dblk * 16 + lr;
          int Fd = ((vrow >> 3) & 7) << 3;
          bf16x8 vf = *(const bf16x8*)(Vt[cur] + vrow * 72 + ((kk * 32 + lg * 8) ^ Fd));
          o[dblk] = __builtin_amdgcn_mfma_f32_16x16x32_bf16(vf, pf, o[dblk], 0, 0, 0);
        }
      }
    }
    cur ^= 1;
  }

  // final cross-group sum reduce (2 shuffles, once)
  lsum += __shfl_xor(lsum, 16);
  lsum += __shfl_xor(lsum, 32);
  float inv = 1.0f / lsum;

  // lane holds O[q=qg][d = dblk*16 + lg*4 + 0..3] -> 4x 8B stores
  bf16_t* ob = out + ((size_t)b * SEQ + qg) * HDIM + h * HEADD;
  #pragma unroll
  for (int dblk = 0; dblk < 4; dblk++) {
    bf16x4 q4;
    #pragma unroll
    for (int r = 0; r < 4; r++) q4[r] = (bf16_t)(o[dblk][r] * inv);
    *(bf16x4*)(ob + dblk * 16 + lg * 4) = q4;
  }
}

extern "C" void kernel_launch(void* const* d_in, const int* in_sizes, int n_in,
                              void* d_out, int out_size, void* d_ws, size_t ws_size,
                              hipStream_t stream) {
  (void)in_sizes; (void)n_in; (void)out_size; (void)ws_size;
  const float* x     = (const float*)d_in[0];
  const float* w_qkv = (const float*)d_in[1];
  const float* b_qkv = (const float*)d_in[2];
  const float* w_out = (const float*)d_in[3];
  const float* b_out = (const float*)d_in[4];
  const float* ln1_g = (const float*)d_in[5];
  const float* ln1_b = (const float*)d_in[6];
  const float* ln2_g = (const float*)d_in[7];
  const float* ln2_b = (const float*)d_in[8];
  const float* w1    = (const float*)d_in[9];
  const float* b1    = (const float*)d_in[10];
  const float* w2    = (const float*)d_in[11];
  const float* b2    = (const float*)d_in[12];
  float* out = (float*)d_out;

  char* ws = (char*)d_ws;
  size_t off = 0;
  auto alloc = [&](size_t bytes) -> void* {
    void* p = ws + off;
    off += (bytes + 255) & ~(size_t)255;
    return p;
  };
  // total ~88 MB
  bf16_t* wqkvT = (bf16_t*)alloc((size_t)3072*1024*2);
  bf16_t* woutT = (bf16_t*)alloc((size_t)1024*1024*2);
  bf16_t* w1T   = (bf16_t*)alloc((size_t)4096*1024*2);
  bf16_t* w2T   = (bf16_t*)alloc((size_t)1024*4096*2);
  bf16_t* ln1o  = (bf16_t*)alloc((size_t)4096*1024*2);   // reused as h2
  bf16_t* qkvb  = (bf16_t*)alloc((size_t)4096*4096*2);   // qkv (4096x3072), reused as gelu-act (4096x4096)
  bf16_t* attno = (bf16_t*)alloc((size_t)4096*1024*2);
  float*  x2    = (float*) alloc((size_t)4096*1024*4);
  bf16_t* h2 = ln1o;
  bf16_t* g  = qkvb;

  dim3 blk(256);
  transpose_cast<<<dim3(3072/32, 1024/32), blk, 0, stream>>>(w_qkv, wqkvT, 1024, 3072);
  transpose_cast<<<dim3(1024/32, 1024/32), blk, 0, stream>>>(w_out, woutT, 1024, 1024);
  transpose_cast<<<dim3(4096/32, 1024/32), blk, 0, stream>>>(w1,    w1T,   1024, 4096);
  transpose_cast<<<dim3(1024/32, 4096/32), blk, 0, stream>>>(w2,    w2T,   4096, 1024);

  ln_kernel<<<4096, blk, 0, stream>>>(x, ln1_g, ln1_b, ln1o);
  gemm_bt<0,128><<<dim3(24, 32), blk, 0, stream>>>(ln1o, wqkvT, b_qkv, nullptr, qkvb, 4096, 3072, 1024);
  attn_kernel<<<512, dim3(512), 0, stream>>>(qkvb, attno);
  gemm_bt<1,64><<<dim3(16, 32), blk, 0, stream>>>(attno, woutT, b_out, x, x2, 4096, 1024, 1024);
  ln_kernel<<<4096, blk, 0, stream>>>(x2, ln2_g, ln2_b, h2);
  gemm_bt<2,128><<<dim3(32, 32), blk, 0, stream>>>(h2, w1T, b1, nullptr, g, 4096, 4096, 1024);
  gemm_bt<1,64><<<dim3(16, 32), blk, 0, stream>>>(g, w2T, b2, x2, out, 4096, 1024, 4096);
}

// Round 8
// 236.071 us; speedup vs baseline: 1.5181x; 1.0698x over previous
//
#include <hip/hip_runtime.h>
#include <hip/hip_bf16.h>

typedef __bf16 bf16_t;
typedef __bf16 bf16x8 __attribute__((ext_vector_type(8)));
typedef __bf16 bf16x4 __attribute__((ext_vector_type(4)));
typedef __bf16 bf16x2 __attribute__((ext_vector_type(2)));
typedef float  f32x4  __attribute__((ext_vector_type(4)));

#define HDIM 1024
#define SEQ  2048
#define NHEAD 16
#define HEADD 64

__device__ __forceinline__ void gld_lds16(const void* g, void* l) {
  __builtin_amdgcn_global_load_lds(
      (const __attribute__((address_space(1))) unsigned int*)g,
      (__attribute__((address_space(3))) unsigned int*)l, 16, 0, 0);
}

// ---------------- LayerNorm(fp32 in) -> bf16 out ----------------
__global__ __launch_bounds__(256) void ln_kernel(const float* __restrict__ x,
                                                 const float* __restrict__ gam,
                                                 const float* __restrict__ bet,
                                                 bf16_t* __restrict__ out) {
  int row = blockIdx.x;
  int t = threadIdx.x;
  const float4* xr = (const float4*)(x + (size_t)row * HDIM);
  float4 v = xr[t];
  float s = v.x + v.y + v.z + v.w;
  float ss = v.x*v.x + v.y*v.y + v.z*v.z + v.w*v.w;
  #pragma unroll
  for (int o = 32; o > 0; o >>= 1) {
    s  += __shfl_xor(s, o);
    ss += __shfl_xor(ss, o);
  }
  __shared__ float red[8];
  int w = t >> 6;
  if ((t & 63) == 0) { red[w*2] = s; red[w*2+1] = ss; }
  __syncthreads();
  s  = red[0] + red[2] + red[4] + red[6];
  ss = red[1] + red[3] + red[5] + red[7];
  float mu  = s * (1.0f / HDIM);
  float var = ss * (1.0f / HDIM) - mu * mu;
  float rstd = rsqrtf(var + 1e-5f);
  float4 g4 = ((const float4*)gam)[t];
  float4 b4 = ((const float4*)bet)[t];
  bf16x4 o4;
  o4[0] = (bf16_t)((v.x - mu) * rstd * g4.x + b4.x);
  o4[1] = (bf16_t)((v.y - mu) * rstd * g4.y + b4.y);
  o4[2] = (bf16_t)((v.z - mu) * rstd * g4.z + b4.z);
  o4[3] = (bf16_t)((v.w - mu) * rstd * g4.w + b4.w);
  *(bf16x4*)(out + (size_t)row * HDIM + t * 4) = o4;
}

// ---------------- W[K][N] fp32 -> W^T[N][K] bf16 ----------------
__global__ __launch_bounds__(256) void transpose_cast(const float* __restrict__ W,
                                                      bf16_t* __restrict__ Wt,
                                                      int Kd, int Nd) {
  __shared__ float tile[32][33];
  int n0 = blockIdx.x * 32, k0 = blockIdx.y * 32;
  int tx = threadIdx.x & 31, ty = threadIdx.x >> 5;
  #pragma unroll
  for (int i = 0; i < 4; i++)
    tile[ty + i*8][tx] = W[(size_t)(k0 + ty + i*8) * Nd + n0 + tx];
  __syncthreads();
  #pragma unroll
  for (int i = 0; i < 4; i++)
    Wt[(size_t)(n0 + ty + i*8) * Kd + k0 + tx] = (bf16_t)tile[tx][ty + i*8];
}

// tanh-form GELU, exp2-based (v_exp_f32 is natively 2^x); ~8 VALU ops
__device__ __forceinline__ float gelu_fast(float x) {
  float y = 0.7978845608f * (x + 0.044715f * x * x * x);
  float u = exp2f(y * 2.885390082f);           // e^(2y)
  float th = 1.0f - 2.0f * __builtin_amdgcn_rcpf(u + 1.0f);
  return 0.5f * x * (1.0f + th);
}

// ---------------- GEMM: C[M][N] = A[M][K](bf16) @ Bt[N][K]^T + bias ----------------
// EPI: 0 = bias, bf16 out; 1 = bias + fp32 residual, fp32 out; 2 = bias + GELU, bf16 out
// BN: 128 or 64.  BK: 32 or 64.
// Double-buffered LDS, prefetch-before-compute, one barrier per K-step,
// XCD-aware block swizzle. LDS tiles use a chunk-XOR swizzle (T2):
//   chunk' = chunk ^ (row & (BK/8-1))
// applied identically on the pre-swizzled global SOURCE (global_load_lds dest
// stays linear, rule #21) and on the ds_read fragment offsets. BK=64 gives a
// fully conflict-free read (8 chunks); BK=32 reduces 8-way -> 4-way.
template<int EPI, int BN, int BK>
__global__ __launch_bounds__(256, 2)
void gemm_bt(const bf16_t* __restrict__ A, const bf16_t* __restrict__ Bt,
             const float* __restrict__ bias, const float* __restrict__ resid,
             void* __restrict__ outp, int M, int N, int K) {
  constexpr int NFRAG = BN / 32;   // 4 for BN=128, 2 for BN=64
  constexpr int CH  = BK / 8;      // 16B chunks per row
  constexpr int SWZ = CH - 1;
  constexpr int RPP = 256 / CH;    // rows staged per pass
  __shared__ bf16_t As[2][128*BK];
  __shared__ bf16_t Bs[2][BN*BK];
  int t = threadIdx.x;
  int w = t >> 6, l = t & 63;
  int wr = w >> 1, wc = w & 1;

  // XCD swizzle: linear bid -> m-major order, chunked per XCD
  int nbx = gridDim.x;
  int bid = blockIdx.y * nbx + blockIdx.x;
  int chunkx = (nbx * gridDim.y) >> 3;
  int nb = (bid & 7) * chunkx + (bid >> 3);
  int bm = nb / nbx, bn = nb % nbx;
  size_t m0 = (size_t)bm * 128, n0 = (size_t)bn * BN;

  f32x4 acc[4][NFRAG];
  #pragma unroll
  for (int m = 0; m < 4; m++)
    #pragma unroll
    for (int n = 0; n < NFRAG; n++) acc[m][n] = (f32x4)(0.0f);

  // staging: thread t covers row srow, swizzled chunk; LDS dest linear (= t*16B)
  int srow = t / CH;
  int scol = ((t & SWZ) ^ (srow & SWZ)) * 8;
  int dsto = t * 8;
  const bf16_t* ag = A  + (m0 + srow) * K + scol;
  const bf16_t* bg = Bt + (n0 + srow) * K + scol;

  int lr = l & 15, lg = l >> 4;

  auto stage = [&](int buf, int k0) {
    #pragma unroll
    for (int p = 0; p < 128/RPP; p++)
      gld_lds16(ag + k0 + (size_t)(p*RPP)*K, &As[buf][dsto + p*RPP*BK]);
    #pragma unroll
    for (int p = 0; p < BN/RPP; p++)
      gld_lds16(bg + k0 + (size_t)(p*RPP)*K, &Bs[buf][dsto + p*RPP*BK]);
  };

  stage(0, 0);
  __syncthreads();
  int cur = 0;
  for (int k0 = 0; k0 < K; k0 += BK) {
    if (k0 + BK < K) stage(cur ^ 1, k0 + BK);   // prefetch next tile first
    #pragma unroll
    for (int kk = 0; kk < BK/32; kk++) {
      bf16x8 af[4], bfr[NFRAG];
      #pragma unroll
      for (int m = 0; m < 4; m++) {
        int row = wr*64 + m*16 + lr;
        int off = row*BK*2 + (((kk*4 + lg) ^ (row & SWZ)) << 4);
        af[m] = *(const bf16x8*)((const char*)&As[cur][0] + off);
      }
      #pragma unroll
      for (int n = 0; n < NFRAG; n++) {
        int row = wc*(BN/2) + n*16 + lr;
        int off = row*BK*2 + (((kk*4 + lg) ^ (row & SWZ)) << 4);
        bfr[n] = *(const bf16x8*)((const char*)&Bs[cur][0] + off);
      }
      #pragma unroll
      for (int m = 0; m < 4; m++)
        #pragma unroll
        for (int n = 0; n < NFRAG; n++)
          acc[m][n] = __builtin_amdgcn_mfma_f32_16x16x32_bf16(af[m], bfr[n], acc[m][n], 0, 0, 0);
    }
    __syncthreads();                             // one barrier per K-step
    cur ^= 1;
  }

  int r0 = (l >> 4) * 4, c0 = l & 15;
  #pragma unroll
  for (int m = 0; m < 4; m++) {
    #pragma unroll
    for (int n = 0; n < NFRAG; n++) {
      size_t row = m0 + wr*64 + m*16 + r0;
      size_t col = n0 + wc*(BN/2) + n*16 + c0;
      float bv = bias[col];
      #pragma unroll
      for (int r = 0; r < 4; r++) {
        float vv = acc[m][n][r] + bv;
        size_t idx = (row + r) * (size_t)N + col;
        if (EPI == 0) {
          ((bf16_t*)outp)[idx] = (bf16_t)vv;
        } else if (EPI == 1) {
          ((float*)outp)[idx] = vv + resid[idx];
        } else {
          ((bf16_t*)outp)[idx] = (bf16_t)gelu_fast(vv);
        }
      }
    }
  }
}

// ---------------- causal flash attention (swapped-QK^T, per-lane-row softmax) ----
// qkv: [4096][3072] bf16, row=(b,s), cols: q=h*64+d, k=1024+h*64+d, v=2048+h*64+d
// out: [4096][1024] bf16 (b,s,h*64+d)
__global__ __launch_bounds__(512, 4)
void attn_kernel(const bf16_t* __restrict__ qkv, bf16_t* __restrict__ out) {
  int idx = blockIdx.x;
  int half = idx >> 8;              // 0 or 1
  int sub = idx & 255;
  int qth = sub >> 5;               // 0..7
  int qt = half ? qth : (15 - qth); // first half: 15..8 (long blocks first)
  int bh = sub & 31;
  int b = bh >> 4, h = bh & 15;
  int t = threadIdx.x, w = t >> 6, l = t & 63;

  __shared__ bf16_t Ks[2][64*64];   // XOR-swizzled [krow][d], double-buffered
  __shared__ bf16_t Vt[2][64*72];   // V^T [d][k] stride 72, k XOR-swizzled by F(d)
  __shared__ bf16_t Ps[8][16*64];   // per-wave P tile [q][k], XOR-swizzled

  const size_t RS = 3 * HDIM;  // 3072
  const bf16_t* qb = qkv + (size_t)b * SEQ * RS + h * HEADD;
  const bf16_t* kb = qb + HDIM;
  const bf16_t* vb = qb + 2 * HDIM;

  int lr = l & 15, lg = l >> 4;
  const float SCALE = 0.125f * 1.44269504f;   // 1/sqrt(64) * log2(e), folded into Q

  bf16x8 qf[2];
  {
    size_t qrow = (size_t)qt * 128 + w * 16 + lr;
    qf[0] = *(const bf16x8*)(qb + qrow * RS + lg * 8);
    qf[1] = *(const bf16x8*)(qb + qrow * RS + 32 + lg * 8);
    #pragma unroll
    for (int i = 0; i < 8; i++) {
      qf[0][i] = (bf16_t)((float)qf[0][i] * SCALE);
      qf[1][i] = (bf16_t)((float)qf[1][i] * SCALE);
    }
  }

  f32x4 o[4];
  #pragma unroll
  for (int d = 0; d < 4; d++) o[d] = (f32x4)(0.0f);
  float m = -1e30f, lsum = 0.0f;

  // staging assignment: 512 threads, 64 rows x 64 cols, one bf16x8 each
  int srow = t >> 3, scol = (t & 7) * 8;
  int Fv = ((scol >> 3) & 7) << 3;            // V^T k-swizzle for this thread's d-group
  int nkt = 2 * qt + 2;

  const bf16_t* kg0 = kb + (size_t)srow * RS + scol;
  const bf16_t* vg0 = vb + (size_t)srow * RS + scol;

  bf16x8 kr = *(const bf16x8*)kg0;
  bf16x8 vr = *(const bf16x8*)vg0;

  int wrow0 = qt * 128 + w * 16;              // wave's first q-row
  int qg = wrow0 + lr;                        // this lane's q-row (global)
  bf16_t* pw = Ps[w];
  int psw = (lr & 7) << 4;                    // P swizzle for this lane's row
  int cur = 0;

  for (int kt = 0; kt < nkt; kt++) {
    { // stage tile kt into LDS[cur]
      int ba = srow * 128 + scol * 2;
      int sw = (srow & 7) << 4;
      *(bf16x8*)((char*)Ks[cur] + (ba ^ sw)) = kr;
      int ksw = srow ^ Fv;
      bf16_t* vt = Vt[cur];
      #pragma unroll
      for (int i = 0; i < 8; i++)
        vt[(scol + i) * 72 + ksw] = vr[i];
    }
    // issue global loads for tile kt+1 — arrive during barrier+compute
    if (kt + 1 < nkt) {
      kr = *(const bf16x8*)(kg0 + (size_t)(kt + 1) * 64 * RS);
      vr = *(const bf16x8*)(vg0 + (size_t)(kt + 1) * 64 * RS);
    }
    __syncthreads();   // single barrier: cur written; cur^1 free (all read it last tile)

    bool skipw = (kt * 64) > (wrow0 + 15);    // wave entirely above diagonal
    if (!skipw) {
      // S^T: lane holds S[q=lr][k = kt*64 + kt2*16 + lg*4 + r]
      f32x4 sc[4];
      #pragma unroll
      for (int kt2 = 0; kt2 < 4; kt2++) {
        sc[kt2] = (f32x4)(0.0f);
        #pragma unroll
        for (int kk = 0; kk < 2; kk++) {
          int row = kt2 * 16 + lr;
          int off = (row * 128 + kk * 64 + lg * 16) ^ ((row & 7) << 4);
          bf16x8 kf = *(const bf16x8*)((char*)Ks[cur] + off);
          sc[kt2] = __builtin_amdgcn_mfma_f32_16x16x32_bf16(kf, qf[kk], sc[kt2], 0, 0, 0);
        }
      }
      // causal mask (diagonal region only)
      if (kt * 64 + 63 > wrow0) {
        #pragma unroll
        for (int kt2 = 0; kt2 < 4; kt2++) {
          #pragma unroll
          for (int r = 0; r < 4; r++) {
            int kcol = kt*64 + kt2*16 + lg*4 + r;
            if (kcol > qg) sc[kt2][r] = -1e30f;
          }
        }
      }
      // row max: in-lane tree + 2 cross-group shuffles
      float tm0 = fmaxf(fmaxf(sc[0][0], sc[0][1]), fmaxf(sc[0][2], sc[0][3]));
      float tm1 = fmaxf(fmaxf(sc[1][0], sc[1][1]), fmaxf(sc[1][2], sc[1][3]));
      float tm2 = fmaxf(fmaxf(sc[2][0], sc[2][1]), fmaxf(sc[2][2], sc[2][3]));
      float tm3 = fmaxf(fmaxf(sc[3][0], sc[3][1]), fmaxf(sc[3][2], sc[3][3]));
      float tm = fmaxf(fmaxf(tm0, tm1), fmaxf(tm2, tm3));
      tm = fmaxf(tm, __shfl_xor(tm, 16));
      tm = fmaxf(tm, __shfl_xor(tm, 32));
      // defer-max: only rescale when some row's max grew past THR=8 (log2 domain)
      if (!__all(tm <= m + 8.0f)) {
        float nm = fmaxf(m, tm);
        float alpha = exp2f(m - nm);
        m = nm;
        lsum *= alpha;
        #pragma unroll
        for (int d = 0; d < 4; d++)
          #pragma unroll
          for (int r = 0; r < 4; r++) o[d][r] *= alpha;
      }
      // P = exp2(S - m); pack bf16x2 pairs -> swizzled LDS (8 b32 writes)
      #pragma unroll
      for (int kt2 = 0; kt2 < 4; kt2++) {
        float p0 = exp2f(sc[kt2][0] - m);
        float p1 = exp2f(sc[kt2][1] - m);
        float p2 = exp2f(sc[kt2][2] - m);
        float p3 = exp2f(sc[kt2][3] - m);
        lsum += (p0 + p1) + (p2 + p3);
        bf16x2 pa; pa[0] = (bf16_t)p0; pa[1] = (bf16_t)p1;
        bf16x2 pb; pb[0] = (bf16_t)p2; pb[1] = (bf16_t)p3;
        int base = lr * 128 + kt2 * 32 + lg * 8;
        *(bf16x2*)((char*)pw + ((base)     ^ psw)) = pa;
        *(bf16x2*)((char*)pw + ((base + 4) ^ psw)) = pb;
      }
      asm volatile("s_waitcnt lgkmcnt(0)" ::: "memory");
      // PV: o[dblk] = mfma(A = V^T frag, B = P frag) -> D[row=d][col=q]
      #pragma unroll
      for (int kk = 0; kk < 2; kk++) {
        int poff = (lr * 128 + kk * 64 + lg * 16) ^ psw;
        bf16x8 pf = *(const bf16x8*)((char*)pw + poff);
        #pragma unroll
        for (int dblk = 0; dblk < 4; dblk++) {
          int vrow = dblk * 16 + lr;
          int Fd = ((vrow >> 3) & 7) << 3;
          bf16x8 vf = *(const bf16x8*)(Vt[cur] + vrow * 72 + ((kk * 32 + lg * 8) ^ Fd));
          o[dblk] = __builtin_amdgcn_mfma_f32_16x16x32_bf16(vf, pf, o[dblk], 0, 0, 0);
        }
      }
    }
    cur ^= 1;
  }

  // final cross-group sum reduce (2 shuffles, once)
  lsum += __shfl_xor(lsum, 16);
  lsum += __shfl_xor(lsum, 32);
  float inv = 1.0f / lsum;

  // lane holds O[q=qg][d = dblk*16 + lg*4 + 0..3] -> 4x 8B stores
  bf16_t* ob = out + ((size_t)b * SEQ + qg) * HDIM + h * HEADD;
  #pragma unroll
  for (int dblk = 0; dblk < 4; dblk++) {
    bf16x4 q4;
    #pragma unroll
    for (int r = 0; r < 4; r++) q4[r] = (bf16_t)(o[dblk][r] * inv);
    *(bf16x4*)(ob + dblk * 16 + lg * 4) = q4;
  }
}

extern "C" void kernel_launch(void* const* d_in, const int* in_sizes, int n_in,
                              void* d_out, int out_size, void* d_ws, size_t ws_size,
                              hipStream_t stream) {
  (void)in_sizes; (void)n_in; (void)out_size; (void)ws_size;
  const float* x     = (const float*)d_in[0];
  const float* w_qkv = (const float*)d_in[1];
  const float* b_qkv = (const float*)d_in[2];
  const float* w_out = (const float*)d_in[3];
  const float* b_out = (const float*)d_in[4];
  const float* ln1_g = (const float*)d_in[5];
  const float* ln1_b = (const float*)d_in[6];
  const float* ln2_g = (const float*)d_in[7];
  const float* ln2_b = (const float*)d_in[8];
  const float* w1    = (const float*)d_in[9];
  const float* b1    = (const float*)d_in[10];
  const float* w2    = (const float*)d_in[11];
  const float* b2    = (const float*)d_in[12];
  float* out = (float*)d_out;

  char* ws = (char*)d_ws;
  size_t off = 0;
  auto alloc = [&](size_t bytes) -> void* {
    void* p = ws + off;
    off += (bytes + 255) & ~(size_t)255;
    return p;
  };
  // total ~88 MB
  bf16_t* wqkvT = (bf16_t*)alloc((size_t)3072*1024*2);
  bf16_t* woutT = (bf16_t*)alloc((size_t)1024*1024*2);
  bf16_t* w1T   = (bf16_t*)alloc((size_t)4096*1024*2);
  bf16_t* w2T   = (bf16_t*)alloc((size_t)1024*4096*2);
  bf16_t* ln1o  = (bf16_t*)alloc((size_t)4096*1024*2);   // reused as h2
  bf16_t* qkvb  = (bf16_t*)alloc((size_t)4096*4096*2);   // qkv (4096x3072), reused as gelu-act (4096x4096)
  bf16_t* attno = (bf16_t*)alloc((size_t)4096*1024*2);
  float*  x2    = (float*) alloc((size_t)4096*1024*4);
  bf16_t* h2 = ln1o;
  bf16_t* g  = qkvb;

  dim3 blk(256);
  transpose_cast<<<dim3(3072/32, 1024/32), blk, 0, stream>>>(w_qkv, wqkvT, 1024, 3072);
  transpose_cast<<<dim3(1024/32, 1024/32), blk, 0, stream>>>(w_out, woutT, 1024, 1024);
  transpose_cast<<<dim3(4096/32, 1024/32), blk, 0, stream>>>(w1,    w1T,   1024, 4096);
  transpose_cast<<<dim3(1024/32, 4096/32), blk, 0, stream>>>(w2,    w2T,   4096, 1024);

  ln_kernel<<<4096, blk, 0, stream>>>(x, ln1_g, ln1_b, ln1o);
  gemm_bt<0,128,32><<<dim3(24, 32), blk, 0, stream>>>(ln1o, wqkvT, b_qkv, nullptr, qkvb, 4096, 3072, 1024);
  attn_kernel<<<512, dim3(512), 0, stream>>>(qkvb, attno);
  gemm_bt<1,64,64><<<dim3(16, 32), blk, 0, stream>>>(attno, woutT, b_out, x, x2, 4096, 1024, 1024);
  ln_kernel<<<4096, blk, 0, stream>>>(x2, ln2_g, ln2_b, h2);
  gemm_bt<2,128,32><<<dim3(32, 32), blk, 0, stream>>>(h2, w1T, b1, nullptr, g, 4096, 4096, 1024);
  gemm_bt<1,64,64><<<dim3(16, 32), blk, 0, stream>>>(g, w2T, b2, x2, out, 4096, 1024, 4096);
}